// Round 1
// baseline (2427.119 us; speedup 1.0000x reference)
//
#include <hip/hip_runtime.h>
#include <stdint.h>

#define N_ROWS 131072
#define DIM 64
#define KB 2048
#define M_ELEMS 8388608  // N_ROWS*DIM

// ---- output offsets (float32 elements, concatenated in return order) ----
#define O_XL   0
#define O_XD   131072
#define O_CL   8519680
#define O_FIT  8519681
#define O_PRE  8519682
#define O_ENT  8519683
#define O_USED 8519684
#define O_UTOT 8519685
#define O_DK   8519686
#define O_NK   8519687
#define O_NKS  8650759
#define O_NKE  8781831
// total out = 8783879

// ---- workspace byte offsets ----
#define A_DBL   0         // 6 doubles: sumS,sumQ,fitAcc,commitAcc,dkAcc,entAcc
#define A_IACC  64        // 2 ints: used_curr, usage_total
#define A_KK    128       // 2048 f32
#define A_XLI   8320      // 131072 i32
#define A_KSUM  532608    // 131072 f32
#define A_KCNT  1056896   // 2048 i32
#define A_KRAND 1065088   // 131072 f32
#define A_KEYS  1589376   // 8 u32
#define A_BITS  1589408   // 131072 u32
#define A_HIST1 2113696   // 65536 u32
#define A_PREF1 2375840
#define A_CUR1  2637984
#define A_PKEY  2900128   // 131072 u32
#define A_PIDX  3424416   // 131072 u32
#define A_RES1  3948704   // 131072 u32
#define A_HIST2 4472992
#define A_PREF2 4735136
#define A_CUR2  4997280
#define A_PERM  5259424   // 2048 u32
#define WS_TOTAL 5267616

// ======================= helpers =======================

__device__ __forceinline__ float block_reduce_sum(float v, float* lds) {
  #pragma unroll
  for (int off = 32; off > 0; off >>= 1) v += __shfl_down(v, off, 64);
  int lane = threadIdx.x & 63, wid = threadIdx.x >> 6;
  if (lane == 0) lds[wid] = v;
  __syncthreads();
  float r = 0.f;
  if (threadIdx.x == 0) {
    int nw = blockDim.x >> 6;
    for (int i = 0; i < nw; ++i) r += lds[i];
  }
  __syncthreads();
  return r;  // valid on thread 0
}

#define TF_ROUND(r) do { x0 += x1; x1 = (x1 << (r)) | (x1 >> (32 - (r))); x1 ^= x0; } while (0)

__device__ __forceinline__ void threefry2x32(uint32_t k0, uint32_t k1,
                                             uint32_t c0, uint32_t c1,
                                             uint32_t& o0, uint32_t& o1) {
  uint32_t k2 = k0 ^ k1 ^ 0x1BD11BDAu;
  uint32_t x0 = c0 + k0, x1 = c1 + k1;
  TF_ROUND(13); TF_ROUND(15); TF_ROUND(26); TF_ROUND(6);
  x0 += k1; x1 += k2 + 1u;
  TF_ROUND(17); TF_ROUND(29); TF_ROUND(16); TF_ROUND(24);
  x0 += k2; x1 += k0 + 2u;
  TF_ROUND(13); TF_ROUND(15); TF_ROUND(26); TF_ROUND(6);
  x0 += k0; x1 += k1 + 3u;
  TF_ROUND(17); TF_ROUND(29); TF_ROUND(16); TF_ROUND(24);
  x0 += k1; x1 += k2 + 4u;
  TF_ROUND(13); TF_ROUND(15); TF_ROUND(26); TF_ROUND(6);
  x0 += k2; x1 += k0 + 5u;
  o0 = x0; o1 = x1;
}

// ======================= kernels =======================

__global__ void k_knorm(const float* __restrict__ k, float* __restrict__ kk) {
  int j = blockIdx.x * blockDim.x + threadIdx.x;
  if (j >= KB) return;
  const float4* kp = (const float4*)(k + (size_t)j * DIM);
  float a = 0.f, b = 0.f, c = 0.f, d = 0.f;
  #pragma unroll
  for (int q = 0; q < 16; ++q) {
    float4 v = kp[q];
    a = fmaf(v.x, v.x, a); b = fmaf(v.y, v.y, b);
    c = fmaf(v.z, v.z, c); d = fmaf(v.w, v.w, d);
  }
  kk[j] = (a + b) + (c + d);
}

__global__ __launch_bounds__(256) void k_prenorm(const float* __restrict__ x,
                                                 double* __restrict__ dbl) {
  __shared__ float lds[8];
  int gid = blockIdx.x * blockDim.x + threadIdx.x;  // 262144 threads, 8 float4 each
  const float4* xp = (const float4*)x;
  int base = gid * 8;
  float s = 0.f, q = 0.f;
  #pragma unroll
  for (int i = 0; i < 8; ++i) {
    float4 v = xp[base + i];
    s += (v.x + v.y) + (v.z + v.w);
    q = fmaf(v.x, v.x, q); q = fmaf(v.y, v.y, q);
    q = fmaf(v.z, v.z, q); q = fmaf(v.w, v.w, q);
  }
  float bs = block_reduce_sum(s, lds);
  float bq = block_reduce_sum(q, lds);
  if (threadIdx.x == 0) {
    atomicAdd(&dbl[0], (double)bs);
    atomicAdd(&dbl[1], (double)bq);
  }
}

__global__ __launch_bounds__(256) void k_main(
    const float* __restrict__ x, const float* __restrict__ k,
    const float* __restrict__ kk, float* __restrict__ out,
    int* __restrict__ xli, double* __restrict__ dbl) {
  __shared__ float lds[8];
  int row = blockIdx.x * blockDim.x + threadIdx.x;
  float xr[DIM];
  {
    const float4* xp = (const float4*)(x + (size_t)row * DIM);
    #pragma unroll
    for (int q = 0; q < 16; ++q) {
      float4 v = xp[q];
      xr[q * 4 + 0] = v.x; xr[q * 4 + 1] = v.y;
      xr[q * 4 + 2] = v.z; xr[q * 4 + 3] = v.w;
    }
  }
  float xx;
  {
    float a = 0.f, b = 0.f, c = 0.f, d = 0.f;
    #pragma unroll
    for (int i = 0; i < DIM; i += 4) {
      a = fmaf(xr[i + 0], xr[i + 0], a); b = fmaf(xr[i + 1], xr[i + 1], b);
      c = fmaf(xr[i + 2], xr[i + 2], c); d = fmaf(xr[i + 3], xr[i + 3], d);
    }
    xx = (a + b) + (c + d);
  }
  float best1 = 3.402823466e38f, best2 = 3.402823466e38f;
  int j1 = 0, j2 = 0;
  for (int j = 0; j < KB; ++j) {
    const float* kr = k + (size_t)j * DIM;   // uniform -> scalar loads
    float a = 0.f, b = 0.f, c = 0.f, d = 0.f;
    #pragma unroll
    for (int i = 0; i < DIM; i += 4) {
      a = fmaf(xr[i + 0], kr[i + 0], a);
      b = fmaf(xr[i + 1], kr[i + 1], b);
      c = fmaf(xr[i + 2], kr[i + 2], c);
      d = fmaf(xr[i + 3], kr[i + 3], d);
    }
    float dot = (a + b) + (c + d);
    float dist = fmaf(-2.f, dot, kk[j]);     // xx added at the end (constant per row)
    if (dist < best1) { best2 = best1; j2 = j1; best1 = dist; j1 = j; }
    else if (dist < best2) { best2 = dist; j2 = j; }
  }
  // fp64 refinement of near-ties (fp32 dot err ~1e-4 << 1e-2 window)
  if (best2 - best1 < 1e-2f) {
    const float* kr1 = k + (size_t)j1 * DIM;
    const float* kr2 = k + (size_t)j2 * DIM;
    double e1 = 0.0, e2 = 0.0;
    #pragma unroll
    for (int i = 0; i < DIM; ++i) {
      double xv = (double)xr[i];
      double a1 = xv - (double)kr1[i];
      double a2 = xv - (double)kr2[i];
      e1 = fma(a1, a1, e1); e2 = fma(a2, a2, e2);
    }
    if (e2 < e1 || (e2 == e1 && j2 < j1)) j1 = j2;
  }
  float full = best1 + xx;
  out[O_XL + row] = (float)j1;
  xli[row] = j1;
  float cl;
  {
    const float4* kp = (const float4*)(k + (size_t)j1 * DIM);
    float4* xd = (float4*)(out + O_XD + (size_t)row * DIM);
    float a = 0.f, b = 0.f, c = 0.f, d = 0.f;
    #pragma unroll
    for (int q = 0; q < 16; ++q) {
      float4 v = kp[q];
      xd[q] = v;
      float dx = v.x - xr[q * 4 + 0], dy = v.y - xr[q * 4 + 1];
      float dz = v.z - xr[q * 4 + 2], dw = v.w - xr[q * 4 + 3];
      a = fmaf(dx, dx, a); b = fmaf(dy, dy, b);
      c = fmaf(dz, dz, c); d = fmaf(dw, dw, d);
    }
    cl = (a + b) + (c + d);
  }
  float bf = block_reduce_sum(full, lds);
  float bc = block_reduce_sum(cl, lds);
  if (threadIdx.x == 0) {
    atomicAdd(&dbl[2], (double)bf);
    atomicAdd(&dbl[3], (double)bc);
  }
}

__global__ __launch_bounds__(256) void k_seg(
    const int* __restrict__ xli, const float* __restrict__ x,
    float* __restrict__ ksum, int* __restrict__ kcnt) {
  __shared__ float acc[4][8][DIM];  // 8 KB
  __shared__ int cnt8[8];
  int tid = threadIdx.x;
  for (int e = tid; e < 4 * 8 * DIM; e += 256) ((float*)acc)[e] = 0.f;
  if (tid < 8) cnt8[tid] = 0;
  __syncthreads();
  int b0 = blockIdx.x * 8;
  int g = tid >> 6;
  for (int i = tid; i < N_ROWS; i += 256) {
    int b = xli[i];
    unsigned lb = (unsigned)(b - b0);
    if (lb < 8u) {
      atomicAdd(&cnt8[lb], 1);
      const float4* xp = (const float4*)(x + (size_t)i * DIM);
      #pragma unroll
      for (int q = 0; q < 16; ++q) {
        float4 v = xp[q];
        atomicAdd(&acc[g][lb][q * 4 + 0], v.x);
        atomicAdd(&acc[g][lb][q * 4 + 1], v.y);
        atomicAdd(&acc[g][lb][q * 4 + 2], v.z);
        atomicAdd(&acc[g][lb][q * 4 + 3], v.w);
      }
    }
  }
  __syncthreads();
  for (int e = tid; e < 8 * DIM; e += 256) {
    int lb = e >> 6, c = e & 63;
    float s = acc[0][lb][c] + acc[1][lb][c] + acc[2][lb][c] + acc[3][lb][c];
    ksum[(size_t)(b0 + lb) * DIM + c] = s;
  }
  if (tid < 8) kcnt[b0 + tid] = cnt8[tid];
}

// ---- JAX threefry permutation replication ----

__global__ void rng_setup(uint32_t* __restrict__ keys) {
  // key(42) = (0,42). permutation does 2 rounds of: key,sub = split(key); sort by bits(sub)
  uint32_t a0, a1, b0, b1;
  threefry2x32(0u, 42u, 0u, 2u, a0, b0);
  threefry2x32(0u, 42u, 1u, 3u, a1, b1);
  // key1=(a0,a1), sub1=(b0,b1)
  uint32_t c0, c1, d0, d1;
  threefry2x32(a0, a1, 0u, 2u, c0, d0);
  threefry2x32(a0, a1, 1u, 3u, c1, d1);
  keys[0] = b0; keys[1] = b1;   // sub1
  keys[2] = d0; keys[3] = d1;   // sub2
}

__global__ void k_bits(const uint32_t* __restrict__ keys, int which,
                       uint32_t* __restrict__ bits) {
  int i = blockIdx.x * blockDim.x + threadIdx.x;  // 65536 threads
  uint32_t y0, y1;
  threefry2x32(keys[which * 2 + 0], keys[which * 2 + 1],
               (uint32_t)i, (uint32_t)(i + 65536), y0, y1);
  bits[i] = y0;
  bits[i + 65536] = y1;
}

__global__ void k_hist(const uint32_t* __restrict__ bits, uint32_t* __restrict__ hist) {
  int i = blockIdx.x * blockDim.x + threadIdx.x;
  atomicAdd(&hist[bits[i] >> 16], 1u);
}

__global__ __launch_bounds__(1024) void k_scan(const uint32_t* __restrict__ hist,
                                               uint32_t* __restrict__ prefix) {
  __shared__ uint32_t part[1024];
  int tid = threadIdx.x;
  int base = tid * 64;
  uint32_t s = 0;
  for (int j = 0; j < 64; ++j) s += hist[base + j];
  part[tid] = s;
  __syncthreads();
  for (int off = 1; off < 1024; off <<= 1) {
    uint32_t v = (tid >= off) ? part[tid - off] : 0u;
    __syncthreads();
    part[tid] += v;
    __syncthreads();
  }
  uint32_t run = (tid > 0) ? part[tid - 1] : 0u;
  for (int j = 0; j < 64; ++j) { prefix[base + j] = run; run += hist[base + j]; }
}

__global__ void k_scatter(const uint32_t* __restrict__ bits, const uint32_t* __restrict__ prefix,
                          uint32_t* __restrict__ cursor, uint32_t* __restrict__ pkey,
                          uint32_t* __restrict__ pidx) {
  int i = blockIdx.x * blockDim.x + threadIdx.x;
  uint32_t key = bits[i];
  uint32_t bin = key >> 16;
  uint32_t pos = prefix[bin] + atomicAdd(&cursor[bin], 1u);
  pkey[pos] = key; pidx[pos] = (uint32_t)i;
}

__global__ void k_rank(const uint32_t* __restrict__ pkey, const uint32_t* __restrict__ pidx,
                       const uint32_t* __restrict__ prefix, const uint32_t* __restrict__ cursor,
                       const uint32_t* __restrict__ srcvals, uint32_t* __restrict__ outv,
                       int limit) {
  int s = blockIdx.x * blockDim.x + threadIdx.x;
  uint32_t myk = pkey[s], myi = pidx[s];
  uint32_t bin = myk >> 16;
  uint32_t start = prefix[bin], cnt = cursor[bin];
  uint32_t r = 0;
  for (uint32_t t = 0; t < cnt; ++t) {
    uint32_t ok = pkey[start + t], oi = pidx[start + t];
    r += (ok < myk || (ok == myk && oi < myi)) ? 1u : 0u;
  }
  uint32_t pos = start + r;
  uint32_t val = srcvals ? srcvals[myi] : myi;
  if (limit == 0) outv[pos] = val;
  else if (pos < (uint32_t)limit) outv[pos] = val;
}

__global__ void k_krand(const uint32_t* __restrict__ perm, const float* __restrict__ x,
                        float* __restrict__ krand) {
  int e = blockIdx.x * blockDim.x + threadIdx.x;  // 131072
  int b = e >> 6, c = e & 63;
  krand[e] = x[(size_t)perm[b] * DIM + c];
}

__global__ __launch_bounds__(1024) void k_bins(
    const int* __restrict__ kcnt, const float* __restrict__ k_elem_in,
    float* __restrict__ out, double* __restrict__ dbl, int* __restrict__ iacc) {
  __shared__ float ent_l[1024];
  __shared__ int u1_l[1024], u2_l[1024];
  const float OMF = (float)(1.0 - 0.99);
  int tid = threadIdx.x;
  float ent = 0.f; int used = 0, usage = 0;
  #pragma unroll
  for (int t = 0; t < 2; ++t) {
    int b = tid + t * 1024;
    float cnt = (float)kcnt[b];
    float ke = 0.99f * k_elem_in[b] + OMF * cnt;
    out[O_NKE + b] = ke;
    float p = cnt * (1.f / 131072.f);
    ent -= p * logf(p + 1e-8f);
    used += (cnt >= 1.f) ? 1 : 0;
    usage += (ke >= 1.f) ? 1 : 0;
  }
  ent_l[tid] = ent; u1_l[tid] = used; u2_l[tid] = usage;
  __syncthreads();
  for (int off = 512; off > 0; off >>= 1) {
    if (tid < off) {
      ent_l[tid] += ent_l[tid + off];
      u1_l[tid] += u1_l[tid + off];
      u2_l[tid] += u2_l[tid + off];
    }
    __syncthreads();
  }
  if (tid == 0) { dbl[5] = (double)ent_l[0]; iacc[0] = u1_l[0]; iacc[1] = u2_l[0]; }
}

__global__ __launch_bounds__(256) void k_elem_kernel(
    const float* __restrict__ ksum_part, const int* __restrict__ kcnt,
    const float* __restrict__ k_sum_in, const float* __restrict__ k_elem_in,
    const float* __restrict__ k_in, const float* __restrict__ krand,
    float* __restrict__ out, double* __restrict__ dbl) {
  __shared__ float lds[8];
  const float OMF = (float)(1.0 - 0.99);
  int e = blockIdx.x * blockDim.x + threadIdx.x;  // 131072
  int b = e >> 6;
  float nks = 0.99f * k_sum_in[e] + OMF * ksum_part[e];
  out[O_NKS + e] = nks;
  float cnt = (float)kcnt[b];
  float ke = 0.99f * k_elem_in[b] + OMF * cnt;
  float nk = (ke >= 1.f) ? (nks / ke) : krand[e];
  out[O_NK + e] = nk;
  float dd = nk - k_in[e];
  float bsum = block_reduce_sum(dd * dd, lds);
  if (threadIdx.x == 0) atomicAdd(&dbl[4], (double)bsum);
}

__global__ void k_scal(const double* __restrict__ dbl, const int* __restrict__ iacc,
                       float* __restrict__ out) {
  double M = (double)M_ELEMS;
  double sumS = dbl[0], sumQ = dbl[1];
  double var = (sumQ - sumS * sumS / M) / M;
  out[O_PRE] = (float)sqrt(var > 0.0 ? var : 0.0);
  out[O_FIT] = (float)(dbl[2] / (double)N_ROWS);
  out[O_CL]  = (float)(dbl[3] / M);
  out[O_DK]  = (float)sqrt(dbl[4] / (double)(KB * DIM));
  out[O_ENT] = (float)dbl[5];
  out[O_USED] = (float)iacc[0];
  out[O_UTOT] = (float)iacc[1];
}

// ======================= launch =======================

extern "C" void kernel_launch(void* const* d_in, const int* in_sizes, int n_in,
                              void* d_out, int out_size, void* d_ws, size_t ws_size,
                              hipStream_t stream) {
  (void)in_sizes; (void)n_in; (void)out_size; (void)ws_size;
  const float* x      = (const float*)d_in[0];
  const float* k      = (const float*)d_in[1];
  const float* k_sum  = (const float*)d_in[2];
  const float* k_elem = (const float*)d_in[3];
  float* out = (float*)d_out;
  char* ws = (char*)d_ws;

  double*   dbl   = (double*)(ws + A_DBL);
  int*      iacc  = (int*)(ws + A_IACC);
  float*    kk    = (float*)(ws + A_KK);
  int*      xli   = (int*)(ws + A_XLI);
  float*    ksum  = (float*)(ws + A_KSUM);
  int*      kcnt  = (int*)(ws + A_KCNT);
  float*    krand = (float*)(ws + A_KRAND);
  uint32_t* keys  = (uint32_t*)(ws + A_KEYS);
  uint32_t* bits  = (uint32_t*)(ws + A_BITS);
  uint32_t* hist1 = (uint32_t*)(ws + A_HIST1);
  uint32_t* pref1 = (uint32_t*)(ws + A_PREF1);
  uint32_t* cur1  = (uint32_t*)(ws + A_CUR1);
  uint32_t* pkey  = (uint32_t*)(ws + A_PKEY);
  uint32_t* pidx  = (uint32_t*)(ws + A_PIDX);
  uint32_t* res1  = (uint32_t*)(ws + A_RES1);
  uint32_t* hist2 = (uint32_t*)(ws + A_HIST2);
  uint32_t* pref2 = (uint32_t*)(ws + A_PREF2);
  uint32_t* cur2  = (uint32_t*)(ws + A_CUR2);
  uint32_t* perm  = (uint32_t*)(ws + A_PERM);

  hipMemsetAsync(d_ws, 0, WS_TOTAL, stream);

  k_knorm<<<8, 256, 0, stream>>>(k, kk);
  k_prenorm<<<1024, 256, 0, stream>>>(x, dbl);
  k_main<<<512, 256, 0, stream>>>(x, k, kk, out, xli, dbl);
  k_seg<<<256, 256, 0, stream>>>(xli, x, ksum, kcnt);

  // jax.random.permutation(key(42), 131072): 2 stable sort rounds
  rng_setup<<<1, 1, 0, stream>>>(keys);
  k_bits<<<256, 256, 0, stream>>>(keys, 0, bits);
  k_hist<<<512, 256, 0, stream>>>(bits, hist1);
  k_scan<<<1, 1024, 0, stream>>>(hist1, pref1);
  k_scatter<<<512, 256, 0, stream>>>(bits, pref1, cur1, pkey, pidx);
  k_rank<<<512, 256, 0, stream>>>(pkey, pidx, pref1, cur1, nullptr, res1, 0);
  k_bits<<<256, 256, 0, stream>>>(keys, 1, bits);
  k_hist<<<512, 256, 0, stream>>>(bits, hist2);
  k_scan<<<1, 1024, 0, stream>>>(hist2, pref2);
  k_scatter<<<512, 256, 0, stream>>>(bits, pref2, cur2, pkey, pidx);
  k_rank<<<512, 256, 0, stream>>>(pkey, pidx, pref2, cur2, res1, perm, 2048);
  k_krand<<<512, 256, 0, stream>>>(perm, x, krand);

  k_bins<<<1, 1024, 0, stream>>>(kcnt, k_elem, out, dbl, iacc);
  k_elem_kernel<<<512, 256, 0, stream>>>(ksum, kcnt, k_sum, k_elem, k, krand, out, dbl);
  k_scal<<<1, 1, 0, stream>>>(dbl, iacc, out);
}

// Round 2
// 1375.764 us; speedup vs baseline: 1.7642x; 1.7642x over previous
//
#include <hip/hip_runtime.h>
#include <stdint.h>

#define N_ROWS 131072
#define DIM 64
#define KB 2048
#define M_ELEMS 8388608  // N_ROWS*DIM

// ---- output offsets (float32 elements, concatenated in return order) ----
#define O_XL   0
#define O_XD   131072
#define O_CL   8519680
#define O_FIT  8519681
#define O_PRE  8519682
#define O_ENT  8519683
#define O_USED 8519684
#define O_UTOT 8519685
#define O_DK   8519686
#define O_NK   8519687
#define O_NKS  8650759
#define O_NKE  8781831
// total out = 8783879

// ---- workspace byte offsets ----
// persistent
#define A_DBL   0         // 6 doubles
#define A_IACC  64        // 2 ints
#define A_KK2   128       // 2048 f32 (0.5*|k|^2)
#define A_XLI   8320      // 131072 i32
#define A_KSUM  532608    // 131072 f32
#define A_KCNT  1056896   // 2048 i32
#define A_KRAND 1065088   // 131072 f32
#define A_PERM  1589376   // 2048 u32
#define A_KEYS  1597568   // 8 u32 (pad to 64)
// phase A (k_main/k_finish) — union region
#define A_PB1   1597632   // 2*131072 f32
#define A_PB2   2646208   // 2*131072 f32
#define A_PJJ   3694784   // 2*131072 u32
// phase B (RNG) — same union region, temporally disjoint
#define A_BITS  1597632   // 131072 u32
#define A_HIST  2121920   // 65536 u32
#define A_PREF  2384064   // 65536 u32
#define A_CUR   2646208   // 65536 u32
#define A_PKEY  2908352   // 131072 u32
#define A_PIDX  3432640   // 131072 u32
#define A_RES1  3956928   // 131072 u32
#define WS_TOTAL 4743360  // < 5267616 proven available in round 1

typedef float f32x8 __attribute__((ext_vector_type(8)));

// ======================= helpers =======================

__device__ __forceinline__ float block_reduce_sum(float v, float* lds) {
  #pragma unroll
  for (int off = 32; off > 0; off >>= 1) v += __shfl_down(v, off, 64);
  int lane = threadIdx.x & 63, wid = threadIdx.x >> 6;
  if (lane == 0) lds[wid] = v;
  __syncthreads();
  float r = 0.f;
  if (threadIdx.x == 0) {
    int nw = blockDim.x >> 6;
    for (int i = 0; i < nw; ++i) r += lds[i];
  }
  __syncthreads();
  return r;  // valid on thread 0
}

#define TF_ROUND(r) do { x0 += x1; x1 = (x1 << (r)) | (x1 >> (32 - (r))); x1 ^= x0; } while (0)

__device__ __forceinline__ void threefry2x32(uint32_t k0, uint32_t k1,
                                             uint32_t c0, uint32_t c1,
                                             uint32_t& o0, uint32_t& o1) {
  uint32_t k2 = k0 ^ k1 ^ 0x1BD11BDAu;
  uint32_t x0 = c0 + k0, x1 = c1 + k1;
  TF_ROUND(13); TF_ROUND(15); TF_ROUND(26); TF_ROUND(6);
  x0 += k1; x1 += k2 + 1u;
  TF_ROUND(17); TF_ROUND(29); TF_ROUND(16); TF_ROUND(24);
  x0 += k2; x1 += k0 + 2u;
  TF_ROUND(13); TF_ROUND(15); TF_ROUND(26); TF_ROUND(6);
  x0 += k0; x1 += k1 + 3u;
  TF_ROUND(17); TF_ROUND(29); TF_ROUND(16); TF_ROUND(24);
  x0 += k1; x1 += k2 + 4u;
  TF_ROUND(13); TF_ROUND(15); TF_ROUND(26); TF_ROUND(6);
  x0 += k2; x1 += k0 + 5u;
  o0 = x0; o1 = x1;
}

// ======================= kernels =======================

__global__ void k_knorm(const float* __restrict__ k, float* __restrict__ kk2) {
  int j = blockIdx.x * blockDim.x + threadIdx.x;
  if (j >= KB) return;
  const float4* kp = (const float4*)(k + (size_t)j * DIM);
  float a = 0.f, b = 0.f, c = 0.f, d = 0.f;
  #pragma unroll
  for (int q = 0; q < 16; ++q) {
    float4 v = kp[q];
    a = fmaf(v.x, v.x, a); b = fmaf(v.y, v.y, b);
    c = fmaf(v.z, v.z, c); d = fmaf(v.w, v.w, d);
  }
  kk2[j] = 0.5f * ((a + b) + (c + d));
}

__global__ __launch_bounds__(256) void k_prenorm(const float* __restrict__ x,
                                                 double* __restrict__ dbl) {
  __shared__ float lds[8];
  int gid = blockIdx.x * blockDim.x + threadIdx.x;  // 262144 threads, 8 float4 each
  const float4* xp = (const float4*)x;
  int base = gid * 8;
  float s = 0.f, q = 0.f;
  #pragma unroll
  for (int i = 0; i < 8; ++i) {
    float4 v = xp[base + i];
    s += (v.x + v.y) + (v.z + v.w);
    q = fmaf(v.x, v.x, q); q = fmaf(v.y, v.y, q);
    q = fmaf(v.z, v.z, q); q = fmaf(v.w, v.w, q);
  }
  float bs = block_reduce_sum(s, lds);
  float bq = block_reduce_sum(q, lds);
  if (threadIdx.x == 0) {
    atomicAdd(&dbl[0], (double)bs);
    atomicAdd(&dbl[1], (double)bq);
  }
}

// score s_j = dot(x,k_j) - 0.5*|k_j|^2 ; argmin dist == argmax score.
// k row broadcast via SGPRs (s_load), per-chunk top-2 tracked per thread.
#define FMA8(KV, B) \
  a0 = fmaf(xr[(B)+0], (KV)[0], a0); \
  a1 = fmaf(xr[(B)+1], (KV)[1], a1); \
  a2 = fmaf(xr[(B)+2], (KV)[2], a2); \
  a3 = fmaf(xr[(B)+3], (KV)[3], a3); \
  a0 = fmaf(xr[(B)+4], (KV)[4], a0); \
  a1 = fmaf(xr[(B)+5], (KV)[5], a1); \
  a2 = fmaf(xr[(B)+6], (KV)[6], a2); \
  a3 = fmaf(xr[(B)+7], (KV)[7], a3);

__global__ __launch_bounds__(256) void k_main(
    const float* __restrict__ x, const float* __restrict__ k,
    const float* __restrict__ kk2, float* __restrict__ xx,
    float* __restrict__ pb1, float* __restrict__ pb2,
    uint32_t* __restrict__ pjj) {
  int tid = threadIdx.x;
  int rowblk = blockIdx.x >> 1;
  int chunk = blockIdx.x & 1;
  int row = rowblk * 256 + tid;

  float xr[DIM];
  {
    const float4* xp = (const float4*)(x + (size_t)row * DIM);
    #pragma unroll
    for (int q = 0; q < 16; ++q) {
      float4 v = xp[q];
      xr[q * 4 + 0] = v.x; xr[q * 4 + 1] = v.y;
      xr[q * 4 + 2] = v.z; xr[q * 4 + 3] = v.w;
    }
  }
  if (chunk == 0) {
    float a = 0.f, b = 0.f, c = 0.f, d = 0.f;
    #pragma unroll
    for (int i = 0; i < DIM; i += 4) {
      a = fmaf(xr[i + 0], xr[i + 0], a); b = fmaf(xr[i + 1], xr[i + 1], b);
      c = fmaf(xr[i + 2], xr[i + 2], c); d = fmaf(xr[i + 3], xr[i + 3], d);
    }
    xx[row] = (a + b) + (c + d);
  }

  int j0 = chunk * (KB / 2);
  uint64_t kptr = (uint64_t)(uintptr_t)k + (uint64_t)j0 * 256ull;
  uint64_t kkptr = (uint64_t)(uintptr_t)kk2 + (uint64_t)j0 * 4ull;
  float b1 = -3.402823466e38f, b2 = -3.402823466e38f;
  int j1i = j0, j2i = j0;

  for (int jj = 0; jj < KB / 2; ++jj) {
    int j = j0 + jj;
    f32x8 kv0, kv1, kv2, kv3, kv4, kv5, kv6, kv7;
    float kkj;
    asm volatile(
        "s_load_dwordx8 %0, %9, 0x0\n\t"
        "s_load_dwordx8 %1, %9, 0x20\n\t"
        "s_load_dwordx8 %2, %9, 0x40\n\t"
        "s_load_dwordx8 %3, %9, 0x60\n\t"
        "s_load_dwordx8 %4, %9, 0x80\n\t"
        "s_load_dwordx8 %5, %9, 0xa0\n\t"
        "s_load_dwordx8 %6, %9, 0xc0\n\t"
        "s_load_dwordx8 %7, %9, 0xe0\n\t"
        "s_load_dword %8, %10, 0x0\n\t"
        "s_waitcnt lgkmcnt(0)"
        : "=&s"(kv0), "=&s"(kv1), "=&s"(kv2), "=&s"(kv3),
          "=&s"(kv4), "=&s"(kv5), "=&s"(kv6), "=&s"(kv7), "=&s"(kkj)
        : "s"(kptr), "s"(kkptr));

    float a0 = -kkj, a1 = 0.f, a2 = 0.f, a3 = 0.f;
    FMA8(kv0, 0); FMA8(kv1, 8); FMA8(kv2, 16); FMA8(kv3, 24);
    FMA8(kv4, 32); FMA8(kv5, 40); FMA8(kv6, 48); FMA8(kv7, 56);
    float s = (a0 + a1) + (a2 + a3);

    bool c1 = s > b1;
    bool c2 = s > b2;
    b2 = c1 ? b1 : (c2 ? s : b2);
    j2i = c1 ? j1i : (c2 ? j : j2i);
    b1 = c1 ? s : b1;
    j1i = c1 ? j : j1i;

    kptr += 256ull; kkptr += 4ull;
  }
  size_t o = (size_t)chunk * N_ROWS + row;
  pb1[o] = b1;
  pb2[o] = b2;
  pjj[o] = ((uint32_t)j1i << 16) | (uint32_t)j2i;
}

__global__ __launch_bounds__(256) void k_finish(
    const float* __restrict__ x, const float* __restrict__ k,
    const float* __restrict__ xx, const float* __restrict__ pb1,
    const float* __restrict__ pb2, const uint32_t* __restrict__ pjj,
    float* __restrict__ out, int* __restrict__ xli,
    double* __restrict__ dbl) {
  __shared__ float lds[8];
  int row = blockIdx.x * blockDim.x + threadIdx.x;

  float s1a = pb1[row], s2a = pb2[row];
  float s1b = pb1[N_ROWS + row], s2b = pb2[N_ROWS + row];
  uint32_t ja = pjj[row], jb = pjj[N_ROWS + row];
  int j1a = (int)(ja >> 16), j2a = (int)(ja & 0xffffu);
  int j1b = (int)(jb >> 16), j2b = (int)(jb & 0xffffu);

  float B1, B2; int J1, J2;
  if (s1b > s1a) {
    B1 = s1b; J1 = j1b;
    if (s1a >= s2b) { B2 = s1a; J2 = j1a; } else { B2 = s2b; J2 = j2b; }
  } else {
    B1 = s1a; J1 = j1a;
    if (s1b >= s2a) { B2 = s1b; J2 = j1b; } else { B2 = s2a; J2 = j2a; }
  }
  float best1 = -2.f * B1;        // dist minus xx, matches prior formula ~1ulp
  float gap = 2.f * (B1 - B2);

  float xr[DIM];
  {
    const float4* xp = (const float4*)(x + (size_t)row * DIM);
    #pragma unroll
    for (int q = 0; q < 16; ++q) {
      float4 v = xp[q];
      xr[q * 4 + 0] = v.x; xr[q * 4 + 1] = v.y;
      xr[q * 4 + 2] = v.z; xr[q * 4 + 3] = v.w;
    }
  }
  if (gap < 1e-2f) {   // fp64 refinement of near-ties
    const float* kr1 = k + (size_t)J1 * DIM;
    const float* kr2 = k + (size_t)J2 * DIM;
    double e1 = 0.0, e2 = 0.0;
    #pragma unroll
    for (int i = 0; i < DIM; ++i) {
      double xv = (double)xr[i];
      double a1 = xv - (double)kr1[i];
      double a2 = xv - (double)kr2[i];
      e1 = fma(a1, a1, e1); e2 = fma(a2, a2, e2);
    }
    if (e2 < e1 || (e2 == e1 && J2 < J1)) J1 = J2;
  }
  xli[row] = J1;
  out[O_XL + row] = (float)J1;

  float cl;
  {
    const float4* kp = (const float4*)(k + (size_t)J1 * DIM);
    float4* xd = (float4*)(out + O_XD + (size_t)row * DIM);
    float a = 0.f, b = 0.f, c = 0.f, d = 0.f;
    #pragma unroll
    for (int q = 0; q < 16; ++q) {
      float4 v = kp[q];
      xd[q] = v;
      float dx = v.x - xr[q * 4 + 0], dy = v.y - xr[q * 4 + 1];
      float dz = v.z - xr[q * 4 + 2], dw = v.w - xr[q * 4 + 3];
      a = fmaf(dx, dx, a); b = fmaf(dy, dy, b);
      c = fmaf(dz, dz, c); d = fmaf(dw, dw, d);
    }
    cl = (a + b) + (c + d);
  }
  float full = best1 + xx[row];
  float bf = block_reduce_sum(full, lds);
  float bc = block_reduce_sum(cl, lds);
  if (threadIdx.x == 0) {
    atomicAdd(&dbl[2], (double)bf);
    atomicAdd(&dbl[3], (double)bc);
  }
}

__global__ __launch_bounds__(256) void k_seg(
    const int* __restrict__ xli, const float* __restrict__ x,
    float* __restrict__ ksum, int* __restrict__ kcnt) {
  __shared__ float acc[4][8][DIM];  // 8 KB
  __shared__ int cnt8[8];
  int tid = threadIdx.x;
  for (int e = tid; e < 4 * 8 * DIM; e += 256) ((float*)acc)[e] = 0.f;
  if (tid < 8) cnt8[tid] = 0;
  __syncthreads();
  int b0 = blockIdx.x * 8;
  int g = tid >> 6;
  for (int i = tid; i < N_ROWS; i += 256) {
    int b = xli[i];
    unsigned lb = (unsigned)(b - b0);
    if (lb < 8u) {
      atomicAdd(&cnt8[lb], 1);
      const float4* xp = (const float4*)(x + (size_t)i * DIM);
      #pragma unroll
      for (int q = 0; q < 16; ++q) {
        float4 v = xp[q];
        atomicAdd(&acc[g][lb][q * 4 + 0], v.x);
        atomicAdd(&acc[g][lb][q * 4 + 1], v.y);
        atomicAdd(&acc[g][lb][q * 4 + 2], v.z);
        atomicAdd(&acc[g][lb][q * 4 + 3], v.w);
      }
    }
  }
  __syncthreads();
  for (int e = tid; e < 8 * DIM; e += 256) {
    int lb = e >> 6, c = e & 63;
    float s = acc[0][lb][c] + acc[1][lb][c] + acc[2][lb][c] + acc[3][lb][c];
    ksum[(size_t)(b0 + lb) * DIM + c] = s;
  }
  if (tid < 8) kcnt[b0 + tid] = cnt8[tid];
}

// ---- JAX threefry permutation replication ----

__global__ void rng_setup(uint32_t* __restrict__ keys) {
  uint32_t a0, a1, b0, b1;
  threefry2x32(0u, 42u, 0u, 2u, a0, b0);
  threefry2x32(0u, 42u, 1u, 3u, a1, b1);
  uint32_t c0, c1, d0, d1;
  threefry2x32(a0, a1, 0u, 2u, c0, d0);
  threefry2x32(a0, a1, 1u, 3u, c1, d1);
  keys[0] = b0; keys[1] = b1;   // sub1
  keys[2] = d0; keys[3] = d1;   // sub2
}

__global__ void k_bits(const uint32_t* __restrict__ keys, int which,
                       uint32_t* __restrict__ bits) {
  int i = blockIdx.x * blockDim.x + threadIdx.x;  // 65536 threads
  uint32_t y0, y1;
  threefry2x32(keys[which * 2 + 0], keys[which * 2 + 1],
               (uint32_t)i, (uint32_t)(i + 65536), y0, y1);
  bits[i] = y0;
  bits[i + 65536] = y1;
}

__global__ void k_hist(const uint32_t* __restrict__ bits, uint32_t* __restrict__ hist) {
  int i = blockIdx.x * blockDim.x + threadIdx.x;
  atomicAdd(&hist[bits[i] >> 16], 1u);
}

__global__ __launch_bounds__(1024) void k_scan(const uint32_t* __restrict__ hist,
                                               uint32_t* __restrict__ prefix) {
  __shared__ uint32_t part[1024];
  int tid = threadIdx.x;
  int base = tid * 64;
  uint32_t s = 0;
  for (int j = 0; j < 64; ++j) s += hist[base + j];
  part[tid] = s;
  __syncthreads();
  for (int off = 1; off < 1024; off <<= 1) {
    uint32_t v = (tid >= off) ? part[tid - off] : 0u;
    __syncthreads();
    part[tid] += v;
    __syncthreads();
  }
  uint32_t run = (tid > 0) ? part[tid - 1] : 0u;
  for (int j = 0; j < 64; ++j) { prefix[base + j] = run; run += hist[base + j]; }
}

__global__ void k_scatter(const uint32_t* __restrict__ bits, const uint32_t* __restrict__ prefix,
                          uint32_t* __restrict__ cursor, uint32_t* __restrict__ pkey,
                          uint32_t* __restrict__ pidx) {
  int i = blockIdx.x * blockDim.x + threadIdx.x;
  uint32_t key = bits[i];
  uint32_t bin = key >> 16;
  uint32_t pos = prefix[bin] + atomicAdd(&cursor[bin], 1u);
  pkey[pos] = key; pidx[pos] = (uint32_t)i;
}

__global__ void k_rank(const uint32_t* __restrict__ pkey, const uint32_t* __restrict__ pidx,
                       const uint32_t* __restrict__ prefix, const uint32_t* __restrict__ cursor,
                       const uint32_t* __restrict__ srcvals, uint32_t* __restrict__ outv,
                       int limit) {
  int s = blockIdx.x * blockDim.x + threadIdx.x;
  uint32_t myk = pkey[s], myi = pidx[s];
  uint32_t bin = myk >> 16;
  uint32_t start = prefix[bin], cnt = cursor[bin];
  uint32_t r = 0;
  for (uint32_t t = 0; t < cnt; ++t) {
    uint32_t ok = pkey[start + t], oi = pidx[start + t];
    r += (ok < myk || (ok == myk && oi < myi)) ? 1u : 0u;
  }
  uint32_t pos = start + r;
  uint32_t val = srcvals ? srcvals[myi] : myi;
  if (limit == 0) outv[pos] = val;
  else if (pos < (uint32_t)limit) outv[pos] = val;
}

__global__ void k_krand(const uint32_t* __restrict__ perm, const float* __restrict__ x,
                        float* __restrict__ krand) {
  int e = blockIdx.x * blockDim.x + threadIdx.x;  // 131072
  int b = e >> 6, c = e & 63;
  krand[e] = x[(size_t)perm[b] * DIM + c];
}

__global__ __launch_bounds__(1024) void k_bins(
    const int* __restrict__ kcnt, const float* __restrict__ k_elem_in,
    float* __restrict__ out, double* __restrict__ dbl, int* __restrict__ iacc) {
  __shared__ float ent_l[1024];
  __shared__ int u1_l[1024], u2_l[1024];
  const float OMF = (float)(1.0 - 0.99);
  int tid = threadIdx.x;
  float ent = 0.f; int used = 0, usage = 0;
  #pragma unroll
  for (int t = 0; t < 2; ++t) {
    int b = tid + t * 1024;
    float cnt = (float)kcnt[b];
    float ke = 0.99f * k_elem_in[b] + OMF * cnt;
    out[O_NKE + b] = ke;
    float p = cnt * (1.f / 131072.f);
    ent -= p * logf(p + 1e-8f);
    used += (cnt >= 1.f) ? 1 : 0;
    usage += (ke >= 1.f) ? 1 : 0;
  }
  ent_l[tid] = ent; u1_l[tid] = used; u2_l[tid] = usage;
  __syncthreads();
  for (int off = 512; off > 0; off >>= 1) {
    if (tid < off) {
      ent_l[tid] += ent_l[tid + off];
      u1_l[tid] += u1_l[tid + off];
      u2_l[tid] += u2_l[tid + off];
    }
    __syncthreads();
  }
  if (tid == 0) { dbl[5] = (double)ent_l[0]; iacc[0] = u1_l[0]; iacc[1] = u2_l[0]; }
}

__global__ __launch_bounds__(256) void k_elem_kernel(
    const float* __restrict__ ksum_part, const int* __restrict__ kcnt,
    const float* __restrict__ k_sum_in, const float* __restrict__ k_elem_in,
    const float* __restrict__ k_in, const float* __restrict__ krand,
    float* __restrict__ out, double* __restrict__ dbl) {
  __shared__ float lds[8];
  const float OMF = (float)(1.0 - 0.99);
  int e = blockIdx.x * blockDim.x + threadIdx.x;  // 131072
  int b = e >> 6;
  float nks = 0.99f * k_sum_in[e] + OMF * ksum_part[e];
  out[O_NKS + e] = nks;
  float cnt = (float)kcnt[b];
  float ke = 0.99f * k_elem_in[b] + OMF * cnt;
  float nk = (ke >= 1.f) ? (nks / ke) : krand[e];
  out[O_NK + e] = nk;
  float dd = nk - k_in[e];
  float bsum = block_reduce_sum(dd * dd, lds);
  if (threadIdx.x == 0) atomicAdd(&dbl[4], (double)bsum);
}

__global__ void k_scal(const double* __restrict__ dbl, const int* __restrict__ iacc,
                       float* __restrict__ out) {
  double M = (double)M_ELEMS;
  double sumS = dbl[0], sumQ = dbl[1];
  double var = (sumQ - sumS * sumS / M) / M;
  out[O_PRE] = (float)sqrt(var > 0.0 ? var : 0.0);
  out[O_FIT] = (float)(dbl[2] / (double)N_ROWS);
  out[O_CL]  = (float)(dbl[3] / M);
  out[O_DK]  = (float)sqrt(dbl[4] / (double)(KB * DIM));
  out[O_ENT] = (float)dbl[5];
  out[O_USED] = (float)iacc[0];
  out[O_UTOT] = (float)iacc[1];
}

// ======================= launch =======================

extern "C" void kernel_launch(void* const* d_in, const int* in_sizes, int n_in,
                              void* d_out, int out_size, void* d_ws, size_t ws_size,
                              hipStream_t stream) {
  (void)in_sizes; (void)n_in; (void)out_size; (void)ws_size;
  const float* x      = (const float*)d_in[0];
  const float* k      = (const float*)d_in[1];
  const float* k_sum  = (const float*)d_in[2];
  const float* k_elem = (const float*)d_in[3];
  float* out = (float*)d_out;
  char* ws = (char*)d_ws;

  double*   dbl   = (double*)(ws + A_DBL);
  int*      iacc  = (int*)(ws + A_IACC);
  float*    kk2   = (float*)(ws + A_KK2);
  int*      xli   = (int*)(ws + A_XLI);
  float*    ksum  = (float*)(ws + A_KSUM);
  int*      kcnt  = (int*)(ws + A_KCNT);
  float*    krand = (float*)(ws + A_KRAND);
  uint32_t* perm  = (uint32_t*)(ws + A_PERM);
  uint32_t* keys  = (uint32_t*)(ws + A_KEYS);
  float*    pb1   = (float*)(ws + A_PB1);
  float*    pb2   = (float*)(ws + A_PB2);
  uint32_t* pjj   = (uint32_t*)(ws + A_PJJ);
  uint32_t* bits  = (uint32_t*)(ws + A_BITS);
  uint32_t* hist  = (uint32_t*)(ws + A_HIST);
  uint32_t* pref  = (uint32_t*)(ws + A_PREF);
  uint32_t* cur   = (uint32_t*)(ws + A_CUR);
  uint32_t* pkey  = (uint32_t*)(ws + A_PKEY);
  uint32_t* pidx  = (uint32_t*)(ws + A_PIDX);
  uint32_t* res1  = (uint32_t*)(ws + A_RES1);
  float*    xx    = out + O_NK;   // scratch; overwritten later by k_elem_kernel

  hipMemsetAsync(ws + A_DBL, 0, 128, stream);  // dbl + iacc accumulators

  k_knorm<<<8, 256, 0, stream>>>(k, kk2);
  k_prenorm<<<1024, 256, 0, stream>>>(x, dbl);
  k_main<<<1024, 256, 0, stream>>>(x, k, kk2, xx, pb1, pb2, pjj);
  k_finish<<<512, 256, 0, stream>>>(x, k, xx, pb1, pb2, pjj, out, xli, dbl);
  k_seg<<<256, 256, 0, stream>>>(xli, x, ksum, kcnt);

  // jax.random.permutation(key(42), 131072): 2 stable sort rounds
  rng_setup<<<1, 1, 0, stream>>>(keys);
  hipMemsetAsync(ws + A_HIST, 0, 786432, stream);  // hist+pref+cur span
  k_bits<<<256, 256, 0, stream>>>(keys, 0, bits);
  k_hist<<<512, 256, 0, stream>>>(bits, hist);
  k_scan<<<1, 1024, 0, stream>>>(hist, pref);
  k_scatter<<<512, 256, 0, stream>>>(bits, pref, cur, pkey, pidx);
  k_rank<<<512, 256, 0, stream>>>(pkey, pidx, pref, cur, nullptr, res1, 0);
  k_bits<<<256, 256, 0, stream>>>(keys, 1, bits);
  hipMemsetAsync(ws + A_HIST, 0, 786432, stream);
  k_hist<<<512, 256, 0, stream>>>(bits, hist);
  k_scan<<<1, 1024, 0, stream>>>(hist, pref);
  k_scatter<<<512, 256, 0, stream>>>(bits, pref, cur, pkey, pidx);
  k_rank<<<512, 256, 0, stream>>>(pkey, pidx, pref, cur, res1, perm, 2048);
  k_krand<<<512, 256, 0, stream>>>(perm, x, krand);

  k_bins<<<1, 1024, 0, stream>>>(kcnt, k_elem, out, dbl, iacc);
  k_elem_kernel<<<512, 256, 0, stream>>>(ksum, kcnt, k_sum, k_elem, k, krand, out, dbl);
  k_scal<<<1, 1, 0, stream>>>(dbl, iacc, out);
}

// Round 3
// 991.444 us; speedup vs baseline: 2.4481x; 1.3876x over previous
//
#include <hip/hip_runtime.h>
#include <stdint.h>

#define N_ROWS 131072
#define DIM 64
#define KB 2048
#define M_ELEMS 8388608  // N_ROWS*DIM

// ---- output offsets (float32 elements, concatenated in return order) ----
#define O_XL   0
#define O_XD   131072
#define O_CL   8519680
#define O_FIT  8519681
#define O_PRE  8519682
#define O_ENT  8519683
#define O_USED 8519684
#define O_UTOT 8519685
#define O_DK   8519686
#define O_NK   8519687
#define O_NKS  8650759
#define O_NKE  8781831

// ---- workspace byte offsets (total must stay <= 5267616, proven in r1) ----
#define A_DBL   0         // doubles: [2]=sum cl, [4]=dk acc, [5]=entropy
#define A_IACC  64        // 2 ints
#define A_CNT   128       // rescan counter
#define A_KK2N  192       // 2048 f32 : -0.5*|k|^2
#define A_KH    8384      // 2048*64 bf16
#define A_KL    270528    // 2048*64 bf16
#define A_XLI   532672    // 131072 i32
#define A_KSUM  1056960   // 131072 f32
#define A_KCNT  1581248   // 2048 i32
#define A_KRAND 1589440   // 131072 f32
#define A_PERM  2113728   // 2048 u32
// phase A (argmin) region:
#define A_PJ1   2121920   // 131072 u32
#define A_PB1   2646208   // 131072 f32
#define A_PB2   3170496   // 131072 f32
#define A_FLAG  3694784   // 131072 u32
// phase B (RNG) overlays phase A (temporally disjoint):
#define A_BITS  2121920   // 131072 u32
#define A_HIST  2646208   // 65536 u32
#define A_PREF  2908352   // 65536 u32
#define A_CUR   3170496   // 65536 u32
#define A_PKEY  3432640   // 131072 u32
#define A_PIDX  3956928   // 131072 u32
#define A_RES1  4481216   // 131072 u32
#define WS_TOTAL 5005504

typedef short bf16x8 __attribute__((ext_vector_type(8)));
typedef float f32x4 __attribute__((ext_vector_type(4)));

// ======================= helpers =======================

__device__ __forceinline__ float block_reduce_sum(float v, float* lds) {
  #pragma unroll
  for (int off = 32; off > 0; off >>= 1) v += __shfl_down(v, off, 64);
  int lane = threadIdx.x & 63, wid = threadIdx.x >> 6;
  if (lane == 0) lds[wid] = v;
  __syncthreads();
  float r = 0.f;
  if (threadIdx.x == 0) {
    int nw = blockDim.x >> 6;
    for (int i = 0; i < nw; ++i) r += lds[i];
  }
  __syncthreads();
  return r;  // valid on thread 0
}

__device__ __forceinline__ unsigned short f2bf_rne(float f) {
  uint32_t u = __float_as_uint(f);
  uint32_t r = u + 0x7FFFu + ((u >> 16) & 1u);
  return (unsigned short)(r >> 16);
}

#define TF_ROUND(r) do { x0 += x1; x1 = (x1 << (r)) | (x1 >> (32 - (r))); x1 ^= x0; } while (0)

__device__ __forceinline__ void threefry2x32(uint32_t k0, uint32_t k1,
                                             uint32_t c0, uint32_t c1,
                                             uint32_t& o0, uint32_t& o1) {
  uint32_t k2 = k0 ^ k1 ^ 0x1BD11BDAu;
  uint32_t x0 = c0 + k0, x1 = c1 + k1;
  TF_ROUND(13); TF_ROUND(15); TF_ROUND(26); TF_ROUND(6);
  x0 += k1; x1 += k2 + 1u;
  TF_ROUND(17); TF_ROUND(29); TF_ROUND(16); TF_ROUND(24);
  x0 += k2; x1 += k0 + 2u;
  TF_ROUND(13); TF_ROUND(15); TF_ROUND(26); TF_ROUND(6);
  x0 += k0; x1 += k1 + 3u;
  TF_ROUND(17); TF_ROUND(29); TF_ROUND(16); TF_ROUND(24);
  x0 += k1; x1 += k2 + 4u;
  TF_ROUND(13); TF_ROUND(15); TF_ROUND(26); TF_ROUND(6);
  x0 += k2; x1 += k0 + 5u;
  o0 = x0; o1 = x1;
}

// ======================= codebook prep =======================

__global__ void k_knorm(const float* __restrict__ k, float* __restrict__ kk2n) {
  int j = blockIdx.x * blockDim.x + threadIdx.x;
  if (j >= KB) return;
  const float4* kp = (const float4*)(k + (size_t)j * DIM);
  float a = 0.f, b = 0.f, c = 0.f, d = 0.f;
  #pragma unroll
  for (int q = 0; q < 16; ++q) {
    float4 v = kp[q];
    a = fmaf(v.x, v.x, a); b = fmaf(v.y, v.y, b);
    c = fmaf(v.z, v.z, c); d = fmaf(v.w, v.w, d);
  }
  kk2n[j] = -0.5f * ((a + b) + (c + d));
}

__global__ void k_decomp(const float* __restrict__ k, unsigned short* __restrict__ kh,
                         unsigned short* __restrict__ kl) {
  int e = blockIdx.x * blockDim.x + threadIdx.x;  // 131072 elements
  float v = k[e];
  unsigned short h = f2bf_rne(v);
  float hf = __uint_as_float((uint32_t)h << 16);
  kh[e] = h;
  kl[e] = f2bf_rne(v - hf);
}

__global__ __launch_bounds__(256) void k_prenorm(const float* __restrict__ x,
                                                 double* __restrict__ dbl) {
  __shared__ float lds[8];
  int gid = blockIdx.x * blockDim.x + threadIdx.x;
  const float4* xp = (const float4*)x;
  int base = gid * 8;
  float s = 0.f, q = 0.f;
  #pragma unroll
  for (int i = 0; i < 8; ++i) {
    float4 v = xp[base + i];
    s += (v.x + v.y) + (v.z + v.w);
    q = fmaf(v.x, v.x, q); q = fmaf(v.y, v.y, q);
    q = fmaf(v.z, v.z, q); q = fmaf(v.w, v.w, q);
  }
  float bs = block_reduce_sum(s, lds);
  float bq = block_reduce_sum(q, lds);
  if (threadIdx.x == 0) {
    atomicAdd(&dbl[0], (double)bs);
    atomicAdd(&dbl[1], (double)bq);
  }
}

// ======================= MFMA argmin =======================
// S^T[code][xrow] = dot(k_code, x_row) - 0.5|k_code|^2, split-bf16:
// S = xh*kh + xh*kl + xl*kh (error ~1e-4 << 0.01 flag window).
// A-frag (codes): lane l -> row=l&15, k=(l>>4)*8+i. B-frag (x): col=l&15, same k.
// C: col(xrow)=l&15, row(code)=(l>>4)*4+reg.
__global__ __launch_bounds__(256) void k_main(
    const float* __restrict__ x, const unsigned short* __restrict__ kh,
    const unsigned short* __restrict__ kl, const float* __restrict__ kk2n,
    float* __restrict__ pb1, float* __restrict__ pb2, uint32_t* __restrict__ pj1) {
  int lane = threadIdx.x & 63;
  int wid = threadIdx.x >> 6;
  int lrow = lane & 15;
  int lk = lane >> 4;          // 0..3
  int lbase = lk * 4;
  int r0 = (blockIdx.x * 4 + wid) * 64;

  // load + decompose x fragments: 4 row-groups x 2 K-halves
  bf16x8 xh[4][2], xl[4][2];
  #pragma unroll
  for (int g = 0; g < 4; ++g) {
    #pragma unroll
    for (int kt = 0; kt < 2; ++kt) {
      const float* xp = x + (size_t)(r0 + g * 16 + lrow) * DIM + kt * 32 + lk * 8;
      float4 v0 = *(const float4*)xp;
      float4 v1 = *(const float4*)(xp + 4);
      float vv[8] = {v0.x, v0.y, v0.z, v0.w, v1.x, v1.y, v1.z, v1.w};
      #pragma unroll
      for (int i = 0; i < 8; ++i) {
        unsigned short h = f2bf_rne(vv[i]);
        float hf = __uint_as_float((uint32_t)h << 16);
        xh[g][kt][i] = (short)h;
        xl[g][kt][i] = (short)f2bf_rne(vv[i] - hf);
      }
    }
  }

  float b1[4], b2[4];
  uint32_t j1[4];
  #pragma unroll
  for (int g = 0; g < 4; ++g) { b1[g] = -3.402823466e38f; b2[g] = -3.402823466e38f; j1[g] = 0; }

  for (int t = 0; t < KB / 16; ++t) {
    int c0 = t * 16;
    size_t abase = (size_t)(c0 + lrow) * DIM + lk * 8;
    bf16x8 ah0 = *(const bf16x8*)(kh + abase);
    bf16x8 ah1 = *(const bf16x8*)(kh + abase + 32);
    bf16x8 al0 = *(const bf16x8*)(kl + abase);
    bf16x8 al1 = *(const bf16x8*)(kl + abase + 32);
    f32x4 kkv = *(const f32x4*)(kk2n + c0 + lbase);
    uint32_t jb = (uint32_t)(c0 + lbase);
    #pragma unroll
    for (int g = 0; g < 4; ++g) {
      f32x4 acc = __builtin_amdgcn_mfma_f32_16x16x32_bf16(ah0, xh[g][0], kkv, 0, 0, 0);
      acc = __builtin_amdgcn_mfma_f32_16x16x32_bf16(ah1, xh[g][1], acc, 0, 0, 0);
      acc = __builtin_amdgcn_mfma_f32_16x16x32_bf16(al0, xh[g][0], acc, 0, 0, 0);
      acc = __builtin_amdgcn_mfma_f32_16x16x32_bf16(al1, xh[g][1], acc, 0, 0, 0);
      acc = __builtin_amdgcn_mfma_f32_16x16x32_bf16(ah0, xl[g][0], acc, 0, 0, 0);
      acc = __builtin_amdgcn_mfma_f32_16x16x32_bf16(ah1, xl[g][1], acc, 0, 0, 0);
      #pragma unroll
      for (int reg = 0; reg < 4; ++reg) {
        float v = acc[reg];
        bool gt = v > b1[g];
        float mn = fminf(v, b1[g]);
        b2[g] = fmaxf(b2[g], mn);
        b1[g] = gt ? v : b1[g];
        j1[g] = gt ? (jb + (uint32_t)reg) : j1[g];
      }
    }
  }

  // merge across the 4 lanes (lane^16, lane^32) sharing one x-row
  #pragma unroll
  for (int g = 0; g < 4; ++g) {
    #pragma unroll
    for (int s = 16; s <= 32; s <<= 1) {
      float ob1 = __shfl_xor(b1[g], s, 64);
      float ob2 = __shfl_xor(b2[g], s, 64);
      uint32_t oj1 = __shfl_xor(j1[g], s, 64);
      bool gt = ob1 > b1[g];
      float mn = fminf(b1[g], ob1);
      b2[g] = fmaxf(fmaxf(b2[g], ob2), mn);
      b1[g] = fmaxf(b1[g], ob1);
      j1[g] = gt ? oj1 : j1[g];
    }
    if (lk == 0) {
      int row = r0 + g * 16 + lrow;
      pb1[row] = b1[g];
      pb2[row] = b2[g];
      pj1[row] = j1[g];
    }
  }
}

__global__ void k_flag(const float* __restrict__ pb1, const float* __restrict__ pb2,
                       const uint32_t* __restrict__ pj1, int* __restrict__ xli,
                       uint32_t* __restrict__ flag, int* __restrict__ cnt) {
  int row = blockIdx.x * blockDim.x + threadIdx.x;
  xli[row] = (int)pj1[row];
  if (pb1[row] - pb2[row] < 0.01f) {  // score gap = dist gap / 2
    int i = atomicAdd(cnt, 1);
    flag[i] = row;
  }
}

// exact fp64 full rescan for near-tie rows; one wave per row
__global__ __launch_bounds__(256) void k_rescan(
    const uint32_t* __restrict__ flag, const int* __restrict__ cnt,
    const float* __restrict__ x, const float* __restrict__ k,
    int* __restrict__ xli) {
  __shared__ float xs[4][64];
  int lane = threadIdx.x & 63;
  int wid = threadIdx.x >> 6;
  int gw = (blockIdx.x * blockDim.x + threadIdx.x) >> 6;
  int n = *cnt;
  for (int fi = gw; fi < n; fi += 1024) {
    int row = flag[fi];
    xs[wid][lane] = x[(size_t)row * DIM + lane];  // wave-synchronous LDS
    double bd = 1e300;
    int bj = 0;
    for (int j = lane; j < KB; j += 64) {
      const float* kr = k + (size_t)j * DIM;
      double e = 0.0;
      #pragma unroll
      for (int d = 0; d < DIM; ++d) {
        double diff = (double)xs[wid][d] - (double)kr[d];
        e = fma(diff, diff, e);
      }
      if (e < bd) { bd = e; bj = j; }
    }
    #pragma unroll
    for (int off = 32; off > 0; off >>= 1) {
      double od = __shfl_down(bd, off, 64);
      int oj = __shfl_down(bj, off, 64);
      if (od < bd || (od == bd && oj < bj)) { bd = od; bj = oj; }
    }
    if (lane == 0) xli[row] = bj;
  }
}

__global__ __launch_bounds__(256) void k_finish(
    const float* __restrict__ x, const float* __restrict__ k,
    const int* __restrict__ xli, float* __restrict__ out,
    double* __restrict__ dbl) {
  __shared__ float lds[8];
  int row = blockIdx.x * blockDim.x + threadIdx.x;
  int j = xli[row];
  out[O_XL + row] = (float)j;
  const float4* xp = (const float4*)(x + (size_t)row * DIM);
  const float4* kp = (const float4*)(k + (size_t)j * DIM);
  float4* xd = (float4*)(out + O_XD + (size_t)row * DIM);
  float a = 0.f, b = 0.f, c = 0.f, d = 0.f;
  #pragma unroll
  for (int q = 0; q < 16; ++q) {
    float4 kv = kp[q];
    float4 xv = xp[q];
    xd[q] = kv;
    float dx = kv.x - xv.x, dy = kv.y - xv.y;
    float dz = kv.z - xv.z, dw = kv.w - xv.w;
    a = fmaf(dx, dx, a); b = fmaf(dy, dy, b);
    c = fmaf(dz, dz, c); d = fmaf(dw, dw, d);
  }
  float cl = (a + b) + (c + d);    // == min dist (fit & commit share this)
  float bc = block_reduce_sum(cl, lds);
  if (threadIdx.x == 0) atomicAdd(&dbl[2], (double)bc);
}

__global__ __launch_bounds__(256) void k_seg(
    const int* __restrict__ xli, const float* __restrict__ x,
    float* __restrict__ ksum, int* __restrict__ kcnt) {
  __shared__ float acc[4][16][DIM];  // 16 KB
  __shared__ int cnt16[16];
  int tid = threadIdx.x;
  for (int e = tid; e < 4 * 16 * DIM; e += 256) ((float*)acc)[e] = 0.f;
  if (tid < 16) cnt16[tid] = 0;
  __syncthreads();
  int b0 = blockIdx.x * 16;
  int g = tid >> 6;
  for (int i = tid; i < N_ROWS; i += 256) {
    int b = xli[i];
    unsigned lb = (unsigned)(b - b0);
    if (lb < 16u) {
      atomicAdd(&cnt16[lb], 1);
      const float4* xp = (const float4*)(x + (size_t)i * DIM);
      #pragma unroll
      for (int q = 0; q < 16; ++q) {
        float4 v = xp[q];
        atomicAdd(&acc[g][lb][q * 4 + 0], v.x);
        atomicAdd(&acc[g][lb][q * 4 + 1], v.y);
        atomicAdd(&acc[g][lb][q * 4 + 2], v.z);
        atomicAdd(&acc[g][lb][q * 4 + 3], v.w);
      }
    }
  }
  __syncthreads();
  for (int e = tid; e < 16 * DIM; e += 256) {
    int lb = e >> 6, c = e & 63;
    float s = acc[0][lb][c] + acc[1][lb][c] + acc[2][lb][c] + acc[3][lb][c];
    ksum[(size_t)(b0 + lb) * DIM + c] = s;
  }
  if (tid < 16) kcnt[b0 + tid] = cnt16[tid];
}

// ---- JAX threefry permutation replication ----

__global__ void k_bits(int which, uint32_t* __restrict__ bits) {
  uint32_t a0, a1, b0, b1;
  threefry2x32(0u, 42u, 0u, 2u, a0, b0);
  threefry2x32(0u, 42u, 1u, 3u, a1, b1);
  uint32_t k0, k1;
  if (which == 0) { k0 = b0; k1 = b1; }
  else {
    uint32_t c0, c1, d0, d1;
    threefry2x32(a0, a1, 0u, 2u, c0, d0);
    threefry2x32(a0, a1, 1u, 3u, c1, d1);
    k0 = d0; k1 = d1;
  }
  int i = blockIdx.x * blockDim.x + threadIdx.x;  // 65536 threads
  uint32_t y0, y1;
  threefry2x32(k0, k1, (uint32_t)i, (uint32_t)(i + 65536), y0, y1);
  bits[i] = y0;
  bits[i + 65536] = y1;
}

__global__ void k_hist(const uint32_t* __restrict__ bits, uint32_t* __restrict__ hist) {
  int i = blockIdx.x * blockDim.x + threadIdx.x;
  atomicAdd(&hist[bits[i] >> 16], 1u);
}

__global__ __launch_bounds__(1024) void k_scan(const uint32_t* __restrict__ hist,
                                               uint32_t* __restrict__ prefix) {
  __shared__ uint32_t part[1024];
  int tid = threadIdx.x;
  int base = tid * 64;
  uint32_t s = 0;
  for (int j = 0; j < 64; ++j) s += hist[base + j];
  part[tid] = s;
  __syncthreads();
  for (int off = 1; off < 1024; off <<= 1) {
    uint32_t v = (tid >= off) ? part[tid - off] : 0u;
    __syncthreads();
    part[tid] += v;
    __syncthreads();
  }
  uint32_t run = (tid > 0) ? part[tid - 1] : 0u;
  for (int j = 0; j < 64; ++j) { prefix[base + j] = run; run += hist[base + j]; }
}

__global__ void k_scatter(const uint32_t* __restrict__ bits, const uint32_t* __restrict__ prefix,
                          uint32_t* __restrict__ cursor, uint32_t* __restrict__ pkey,
                          uint32_t* __restrict__ pidx) {
  int i = blockIdx.x * blockDim.x + threadIdx.x;
  uint32_t key = bits[i];
  uint32_t bin = key >> 16;
  uint32_t pos = prefix[bin] + atomicAdd(&cursor[bin], 1u);
  pkey[pos] = key; pidx[pos] = (uint32_t)i;
}

__global__ void k_rank(const uint32_t* __restrict__ pkey, const uint32_t* __restrict__ pidx,
                       const uint32_t* __restrict__ prefix, const uint32_t* __restrict__ cursor,
                       const uint32_t* __restrict__ srcvals, uint32_t* __restrict__ outv,
                       int limit) {
  int s = blockIdx.x * blockDim.x + threadIdx.x;
  uint32_t myk = pkey[s], myi = pidx[s];
  uint32_t bin = myk >> 16;
  uint32_t start = prefix[bin], cntb = cursor[bin];
  uint32_t r = 0;
  for (uint32_t t = 0; t < cntb; ++t) {
    uint32_t ok = pkey[start + t], oi = pidx[start + t];
    r += (ok < myk || (ok == myk && oi < myi)) ? 1u : 0u;
  }
  uint32_t pos = start + r;
  uint32_t val = srcvals ? srcvals[myi] : myi;
  if (limit == 0) outv[pos] = val;
  else if (pos < (uint32_t)limit) outv[pos] = val;
}

__global__ void k_krand(const uint32_t* __restrict__ perm, const float* __restrict__ x,
                        float* __restrict__ krand) {
  int e = blockIdx.x * blockDim.x + threadIdx.x;
  int b = e >> 6, c = e & 63;
  krand[e] = x[(size_t)perm[b] * DIM + c];
}

__global__ __launch_bounds__(1024) void k_bins(
    const int* __restrict__ kcnt, const float* __restrict__ k_elem_in,
    float* __restrict__ out, double* __restrict__ dbl, int* __restrict__ iacc) {
  __shared__ float ent_l[1024];
  __shared__ int u1_l[1024], u2_l[1024];
  const float OMF = (float)(1.0 - 0.99);
  int tid = threadIdx.x;
  float ent = 0.f; int used = 0, usage = 0;
  #pragma unroll
  for (int t = 0; t < 2; ++t) {
    int b = tid + t * 1024;
    float cnt = (float)kcnt[b];
    float ke = 0.99f * k_elem_in[b] + OMF * cnt;
    out[O_NKE + b] = ke;
    float p = cnt * (1.f / 131072.f);
    ent -= p * logf(p + 1e-8f);
    used += (cnt >= 1.f) ? 1 : 0;
    usage += (ke >= 1.f) ? 1 : 0;
  }
  ent_l[tid] = ent; u1_l[tid] = used; u2_l[tid] = usage;
  __syncthreads();
  for (int off = 512; off > 0; off >>= 1) {
    if (tid < off) {
      ent_l[tid] += ent_l[tid + off];
      u1_l[tid] += u1_l[tid + off];
      u2_l[tid] += u2_l[tid + off];
    }
    __syncthreads();
  }
  if (tid == 0) { dbl[5] = (double)ent_l[0]; iacc[0] = u1_l[0]; iacc[1] = u2_l[0]; }
}

__global__ __launch_bounds__(256) void k_elem_kernel(
    const float* __restrict__ ksum_part, const int* __restrict__ kcnt,
    const float* __restrict__ k_sum_in, const float* __restrict__ k_elem_in,
    const float* __restrict__ k_in, const float* __restrict__ krand,
    float* __restrict__ out, double* __restrict__ dbl) {
  __shared__ float lds[8];
  const float OMF = (float)(1.0 - 0.99);
  int e = blockIdx.x * blockDim.x + threadIdx.x;
  int b = e >> 6;
  float nks = 0.99f * k_sum_in[e] + OMF * ksum_part[e];
  out[O_NKS + e] = nks;
  float cnt = (float)kcnt[b];
  float ke = 0.99f * k_elem_in[b] + OMF * cnt;
  float nk = (ke >= 1.f) ? (nks / ke) : krand[e];
  out[O_NK + e] = nk;
  float dd = nk - k_in[e];
  float bsum = block_reduce_sum(dd * dd, lds);
  if (threadIdx.x == 0) atomicAdd(&dbl[4], (double)bsum);
}

__global__ void k_scal(const double* __restrict__ dbl, const int* __restrict__ iacc,
                       float* __restrict__ out) {
  double M = (double)M_ELEMS;
  double sumS = dbl[0], sumQ = dbl[1];
  double var = (sumQ - sumS * sumS / M) / M;
  out[O_PRE] = (float)sqrt(var > 0.0 ? var : 0.0);
  out[O_FIT] = (float)(dbl[2] / (double)N_ROWS);
  out[O_CL]  = (float)(dbl[2] / M);
  out[O_DK]  = (float)sqrt(dbl[4] / (double)(KB * DIM));
  out[O_ENT] = (float)dbl[5];
  out[O_USED] = (float)iacc[0];
  out[O_UTOT] = (float)iacc[1];
}

// ======================= launch =======================

extern "C" void kernel_launch(void* const* d_in, const int* in_sizes, int n_in,
                              void* d_out, int out_size, void* d_ws, size_t ws_size,
                              hipStream_t stream) {
  (void)in_sizes; (void)n_in; (void)out_size; (void)ws_size;
  const float* x      = (const float*)d_in[0];
  const float* k      = (const float*)d_in[1];
  const float* k_sum  = (const float*)d_in[2];
  const float* k_elem = (const float*)d_in[3];
  float* out = (float*)d_out;
  char* ws = (char*)d_ws;

  double*   dbl   = (double*)(ws + A_DBL);
  int*      iacc  = (int*)(ws + A_IACC);
  int*      cnt   = (int*)(ws + A_CNT);
  float*    kk2n  = (float*)(ws + A_KK2N);
  unsigned short* kh = (unsigned short*)(ws + A_KH);
  unsigned short* kl = (unsigned short*)(ws + A_KL);
  int*      xli   = (int*)(ws + A_XLI);
  float*    ksum  = (float*)(ws + A_KSUM);
  int*      kcnt  = (int*)(ws + A_KCNT);
  float*    krand = (float*)(ws + A_KRAND);
  uint32_t* perm  = (uint32_t*)(ws + A_PERM);
  uint32_t* pj1   = (uint32_t*)(ws + A_PJ1);
  float*    pb1   = (float*)(ws + A_PB1);
  float*    pb2   = (float*)(ws + A_PB2);
  uint32_t* flag  = (uint32_t*)(ws + A_FLAG);
  uint32_t* bits  = (uint32_t*)(ws + A_BITS);
  uint32_t* hist  = (uint32_t*)(ws + A_HIST);
  uint32_t* pref  = (uint32_t*)(ws + A_PREF);
  uint32_t* cur   = (uint32_t*)(ws + A_CUR);
  uint32_t* pkey  = (uint32_t*)(ws + A_PKEY);
  uint32_t* pidx  = (uint32_t*)(ws + A_PIDX);
  uint32_t* res1  = (uint32_t*)(ws + A_RES1);

  hipMemsetAsync(ws + A_DBL, 0, 192, stream);  // dbl + iacc + cnt

  k_knorm<<<8, 256, 0, stream>>>(k, kk2n);
  k_decomp<<<512, 256, 0, stream>>>(k, kh, kl);
  k_prenorm<<<1024, 256, 0, stream>>>(x, dbl);
  k_main<<<512, 256, 0, stream>>>(x, kh, kl, kk2n, pb1, pb2, pj1);
  k_flag<<<512, 256, 0, stream>>>(pb1, pb2, pj1, xli, flag, cnt);
  k_rescan<<<256, 256, 0, stream>>>(flag, cnt, x, k, xli);
  k_finish<<<512, 256, 0, stream>>>(x, k, xli, out, dbl);
  k_seg<<<128, 256, 0, stream>>>(xli, x, ksum, kcnt);

  // jax.random.permutation(key(42), 131072): 2 stable sort rounds
  k_bits<<<256, 256, 0, stream>>>(0, bits);
  hipMemsetAsync(ws + A_HIST, 0, 786432, stream);
  k_hist<<<512, 256, 0, stream>>>(bits, hist);
  k_scan<<<1, 1024, 0, stream>>>(hist, pref);
  k_scatter<<<512, 256, 0, stream>>>(bits, pref, cur, pkey, pidx);
  k_rank<<<512, 256, 0, stream>>>(pkey, pidx, pref, cur, nullptr, res1, 0);
  k_bits<<<256, 256, 0, stream>>>(1, bits);
  hipMemsetAsync(ws + A_HIST, 0, 786432, stream);
  k_hist<<<512, 256, 0, stream>>>(bits, hist);
  k_scan<<<1, 1024, 0, stream>>>(hist, pref);
  k_scatter<<<512, 256, 0, stream>>>(bits, pref, cur, pkey, pidx);
  k_rank<<<512, 256, 0, stream>>>(pkey, pidx, pref, cur, res1, perm, 2048);
  k_krand<<<512, 256, 0, stream>>>(perm, x, krand);

  k_bins<<<1, 1024, 0, stream>>>(kcnt, k_elem, out, dbl, iacc);
  k_elem_kernel<<<512, 256, 0, stream>>>(ksum, kcnt, k_sum, k_elem, k, krand, out, dbl);
  k_scal<<<1, 1, 0, stream>>>(dbl, iacc, out);
}

// Round 4
// 791.911 us; speedup vs baseline: 3.0649x; 1.2520x over previous
//
#include <hip/hip_runtime.h>
#include <stdint.h>

#define N_ROWS 131072
#define DIM 64
#define KB 2048
#define M_ELEMS 8388608  // N_ROWS*DIM

// ---- output offsets (float32 elements, concatenated in return order) ----
#define O_XL   0
#define O_XD   131072
#define O_CL   8519680
#define O_FIT  8519681
#define O_PRE  8519682
#define O_ENT  8519683
#define O_USED 8519684
#define O_UTOT 8519685
#define O_DK   8519686
#define O_NK   8519687
#define O_NKS  8650759
#define O_NKE  8781831

// ---- workspace byte offsets (total must stay <= 5267616, proven in r1) ----
#define A_DBL   0         // doubles: [0]=sumS,[1]=sumQ,[2]=sum cl,[4]=dk acc,[5]=entropy
#define A_IACC  64        // 2 ints
#define A_CNT   128       // rescan counter
#define A_KK2N  192       // 2048 f32 : -0.5*|k|^2
#define A_KH    8384      // 2048*64 bf16
#define A_KL    270528    // 2048*64 bf16
#define A_XLI   532672    // 131072 i32
#define A_KSUM  1056960   // 131072 f32
#define A_KCNT  1581248   // 2048 i32
#define A_KRAND 1589440   // 131072 f32
#define A_PERM  2113728   // 2048 u32
// phase A (argmin) region:
#define A_PJ1   2121920   // 131072 u32
#define A_PB1   2646208   // 131072 f32
#define A_PB2   3170496   // 131072 f32
#define A_FLAG  3694784   // 131072 u32
// phase A2 (segment sort) overlays pb1/pb2 (dead after k_flag):
#define A_ROWL  2646208   // 131072 u32 rowlist
#define A_BOFF  3170496   // 2048 u32 bin offsets
#define A_BCUR  3178688   // 2048 u32 bin cursors
// phase B (RNG) overlays phase A (temporally disjoint):
#define A_BITS  2121920   // 131072 u32
#define A_HIST  2646208   // 65536 u32
#define A_PREF  2908352   // 65536 u32
#define A_CUR   3170496   // 65536 u32
#define A_PKEY  3432640   // 131072 u32
#define A_PIDX  3956928   // 131072 u32
#define A_RES1  4481216   // 131072 u32
#define WS_TOTAL 5005504

typedef short bf16x8 __attribute__((ext_vector_type(8)));
typedef float f32x4 __attribute__((ext_vector_type(4)));

// ======================= helpers =======================

__device__ __forceinline__ float block_reduce_sum(float v, float* lds) {
  #pragma unroll
  for (int off = 32; off > 0; off >>= 1) v += __shfl_down(v, off, 64);
  int lane = threadIdx.x & 63, wid = threadIdx.x >> 6;
  if (lane == 0) lds[wid] = v;
  __syncthreads();
  float r = 0.f;
  if (threadIdx.x == 0) {
    int nw = blockDim.x >> 6;
    for (int i = 0; i < nw; ++i) r += lds[i];
  }
  __syncthreads();
  return r;  // valid on thread 0
}

__device__ __forceinline__ unsigned short f2bf_rne(float f) {
  uint32_t u = __float_as_uint(f);
  uint32_t r = u + 0x7FFFu + ((u >> 16) & 1u);
  return (unsigned short)(r >> 16);
}

#define TF_ROUND(r) do { x0 += x1; x1 = (x1 << (r)) | (x1 >> (32 - (r))); x1 ^= x0; } while (0)

__device__ __forceinline__ void threefry2x32(uint32_t k0, uint32_t k1,
                                             uint32_t c0, uint32_t c1,
                                             uint32_t& o0, uint32_t& o1) {
  uint32_t k2 = k0 ^ k1 ^ 0x1BD11BDAu;
  uint32_t x0 = c0 + k0, x1 = c1 + k1;
  TF_ROUND(13); TF_ROUND(15); TF_ROUND(26); TF_ROUND(6);
  x0 += k1; x1 += k2 + 1u;
  TF_ROUND(17); TF_ROUND(29); TF_ROUND(16); TF_ROUND(24);
  x0 += k2; x1 += k0 + 2u;
  TF_ROUND(13); TF_ROUND(15); TF_ROUND(26); TF_ROUND(6);
  x0 += k0; x1 += k1 + 3u;
  TF_ROUND(17); TF_ROUND(29); TF_ROUND(16); TF_ROUND(24);
  x0 += k1; x1 += k2 + 4u;
  TF_ROUND(13); TF_ROUND(15); TF_ROUND(26); TF_ROUND(6);
  x0 += k2; x1 += k0 + 5u;
  o0 = x0; o1 = x1;
}

// ======================= codebook prep =======================

__global__ void k_knorm(const float* __restrict__ k, float* __restrict__ kk2n) {
  int j = blockIdx.x * blockDim.x + threadIdx.x;
  if (j >= KB) return;
  const float4* kp = (const float4*)(k + (size_t)j * DIM);
  float a = 0.f, b = 0.f, c = 0.f, d = 0.f;
  #pragma unroll
  for (int q = 0; q < 16; ++q) {
    float4 v = kp[q];
    a = fmaf(v.x, v.x, a); b = fmaf(v.y, v.y, b);
    c = fmaf(v.z, v.z, c); d = fmaf(v.w, v.w, d);
  }
  kk2n[j] = -0.5f * ((a + b) + (c + d));
}

__global__ void k_decomp(const float* __restrict__ k, unsigned short* __restrict__ kh,
                         unsigned short* __restrict__ kl) {
  int e = blockIdx.x * blockDim.x + threadIdx.x;  // 131072 elements
  float v = k[e];
  unsigned short h = f2bf_rne(v);
  float hf = __uint_as_float((uint32_t)h << 16);
  kh[e] = h;
  kl[e] = f2bf_rne(v - hf);
}

__global__ __launch_bounds__(256) void k_prenorm(const float* __restrict__ x,
                                                 double* __restrict__ dbl) {
  __shared__ float lds[8];
  int gid = blockIdx.x * blockDim.x + threadIdx.x;
  const float4* xp = (const float4*)x;
  int base = gid * 8;
  float s = 0.f, q = 0.f;
  #pragma unroll
  for (int i = 0; i < 8; ++i) {
    float4 v = xp[base + i];
    s += (v.x + v.y) + (v.z + v.w);
    q = fmaf(v.x, v.x, q); q = fmaf(v.y, v.y, q);
    q = fmaf(v.z, v.z, q); q = fmaf(v.w, v.w, q);
  }
  float bs = block_reduce_sum(s, lds);
  float bq = block_reduce_sum(q, lds);
  if (threadIdx.x == 0) {
    atomicAdd(&dbl[0], (double)bs);
    atomicAdd(&dbl[1], (double)bq);
  }
}

// ======================= MFMA argmin =======================
// S^T[code][xrow] = dot(k_code, x_row) - 0.5|k_code|^2, split-bf16:
// S = xh*kh + xh*kl + xl*kh (error ~1e-4 << 0.01 flag window).
__global__ __launch_bounds__(256) void k_main(
    const float* __restrict__ x, const unsigned short* __restrict__ kh,
    const unsigned short* __restrict__ kl, const float* __restrict__ kk2n,
    float* __restrict__ pb1, float* __restrict__ pb2, uint32_t* __restrict__ pj1) {
  int lane = threadIdx.x & 63;
  int wid = threadIdx.x >> 6;
  int lrow = lane & 15;
  int lk = lane >> 4;          // 0..3
  int lbase = lk * 4;
  int r0 = (blockIdx.x * 4 + wid) * 64;

  bf16x8 xh[4][2], xl[4][2];
  #pragma unroll
  for (int g = 0; g < 4; ++g) {
    #pragma unroll
    for (int kt = 0; kt < 2; ++kt) {
      const float* xp = x + (size_t)(r0 + g * 16 + lrow) * DIM + kt * 32 + lk * 8;
      float4 v0 = *(const float4*)xp;
      float4 v1 = *(const float4*)(xp + 4);
      float vv[8] = {v0.x, v0.y, v0.z, v0.w, v1.x, v1.y, v1.z, v1.w};
      #pragma unroll
      for (int i = 0; i < 8; ++i) {
        unsigned short h = f2bf_rne(vv[i]);
        float hf = __uint_as_float((uint32_t)h << 16);
        xh[g][kt][i] = (short)h;
        xl[g][kt][i] = (short)f2bf_rne(vv[i] - hf);
      }
    }
  }

  float b1[4], b2[4];
  uint32_t j1[4];
  #pragma unroll
  for (int g = 0; g < 4; ++g) { b1[g] = -3.402823466e38f; b2[g] = -3.402823466e38f; j1[g] = 0; }

  for (int t = 0; t < KB / 16; ++t) {
    int c0 = t * 16;
    size_t abase = (size_t)(c0 + lrow) * DIM + lk * 8;
    bf16x8 ah0 = *(const bf16x8*)(kh + abase);
    bf16x8 ah1 = *(const bf16x8*)(kh + abase + 32);
    bf16x8 al0 = *(const bf16x8*)(kl + abase);
    bf16x8 al1 = *(const bf16x8*)(kl + abase + 32);
    f32x4 kkv = *(const f32x4*)(kk2n + c0 + lbase);
    uint32_t jb = (uint32_t)(c0 + lbase);
    #pragma unroll
    for (int g = 0; g < 4; ++g) {
      f32x4 acc = __builtin_amdgcn_mfma_f32_16x16x32_bf16(ah0, xh[g][0], kkv, 0, 0, 0);
      acc = __builtin_amdgcn_mfma_f32_16x16x32_bf16(ah1, xh[g][1], acc, 0, 0, 0);
      acc = __builtin_amdgcn_mfma_f32_16x16x32_bf16(al0, xh[g][0], acc, 0, 0, 0);
      acc = __builtin_amdgcn_mfma_f32_16x16x32_bf16(al1, xh[g][1], acc, 0, 0, 0);
      acc = __builtin_amdgcn_mfma_f32_16x16x32_bf16(ah0, xl[g][0], acc, 0, 0, 0);
      acc = __builtin_amdgcn_mfma_f32_16x16x32_bf16(ah1, xl[g][1], acc, 0, 0, 0);
      #pragma unroll
      for (int reg = 0; reg < 4; ++reg) {
        float v = acc[reg];
        bool gt = v > b1[g];
        float mn = fminf(v, b1[g]);
        b2[g] = fmaxf(b2[g], mn);
        b1[g] = gt ? v : b1[g];
        j1[g] = gt ? (jb + (uint32_t)reg) : j1[g];
      }
    }
  }

  #pragma unroll
  for (int g = 0; g < 4; ++g) {
    #pragma unroll
    for (int s = 16; s <= 32; s <<= 1) {
      float ob1 = __shfl_xor(b1[g], s, 64);
      float ob2 = __shfl_xor(b2[g], s, 64);
      uint32_t oj1 = __shfl_xor(j1[g], s, 64);
      bool gt = ob1 > b1[g];
      float mn = fminf(b1[g], ob1);
      b2[g] = fmaxf(fmaxf(b2[g], ob2), mn);
      b1[g] = fmaxf(b1[g], ob1);
      j1[g] = gt ? oj1 : j1[g];
    }
    if (lk == 0) {
      int row = r0 + g * 16 + lrow;
      pb1[row] = b1[g];
      pb2[row] = b2[g];
      pj1[row] = j1[g];
    }
  }
}

__global__ void k_flag(const float* __restrict__ pb1, const float* __restrict__ pb2,
                       const uint32_t* __restrict__ pj1, int* __restrict__ xli,
                       uint32_t* __restrict__ flag, int* __restrict__ cnt) {
  int row = blockIdx.x * blockDim.x + threadIdx.x;
  xli[row] = (int)pj1[row];
  if (pb1[row] - pb2[row] < 0.01f) {  // score gap = dist gap / 2
    int i = atomicAdd(cnt, 1);
    flag[i] = row;
  }
}

// exact fp64 full rescan for near-tie rows; one wave per row
__global__ __launch_bounds__(256) void k_rescan(
    const uint32_t* __restrict__ flag, const int* __restrict__ cnt,
    const float* __restrict__ x, const float* __restrict__ k,
    int* __restrict__ xli) {
  __shared__ float xs[4][64];
  int lane = threadIdx.x & 63;
  int wid = threadIdx.x >> 6;
  int gw = (blockIdx.x * blockDim.x + threadIdx.x) >> 6;
  int n = *cnt;
  for (int fi = gw; fi < n; fi += 1024) {
    int row = flag[fi];
    xs[wid][lane] = x[(size_t)row * DIM + lane];  // wave-synchronous LDS
    double bd = 1e300;
    int bj = 0;
    for (int j = lane; j < KB; j += 64) {
      const float* kr = k + (size_t)j * DIM;
      double e = 0.0;
      #pragma unroll
      for (int d = 0; d < DIM; ++d) {
        double diff = (double)xs[wid][d] - (double)kr[d];
        e = fma(diff, diff, e);
      }
      if (e < bd) { bd = e; bj = j; }
    }
    #pragma unroll
    for (int off = 32; off > 0; off >>= 1) {
      double od = __shfl_down(bd, off, 64);
      int oj = __shfl_down(bj, off, 64);
      if (od < bd || (od == bd && oj < bj)) { bd = od; bj = oj; }
    }
    if (lane == 0) xli[row] = bj;
  }
}

__global__ __launch_bounds__(256) void k_finish(
    const float* __restrict__ x, const float* __restrict__ k,
    const int* __restrict__ xli, float* __restrict__ out,
    double* __restrict__ dbl) {
  __shared__ float lds[8];
  int row = blockIdx.x * blockDim.x + threadIdx.x;
  int j = xli[row];
  out[O_XL + row] = (float)j;
  const float4* xp = (const float4*)(x + (size_t)row * DIM);
  const float4* kp = (const float4*)(k + (size_t)j * DIM);
  float4* xd = (float4*)(out + O_XD + (size_t)row * DIM);
  float a = 0.f, b = 0.f, c = 0.f, d = 0.f;
  #pragma unroll
  for (int q = 0; q < 16; ++q) {
    float4 kv = kp[q];
    float4 xv = xp[q];
    xd[q] = kv;
    float dx = kv.x - xv.x, dy = kv.y - xv.y;
    float dz = kv.z - xv.z, dw = kv.w - xv.w;
    a = fmaf(dx, dx, a); b = fmaf(dy, dy, b);
    c = fmaf(dz, dz, c); d = fmaf(dw, dw, d);
  }
  float cl = (a + b) + (c + d);    // == min dist (fit & commit share this)
  float bc = block_reduce_sum(cl, lds);
  if (threadIdx.x == 0) atomicAdd(&dbl[2], (double)bc);
}

// ======================= segment sum via counting sort =======================

__global__ void k_hist_rows(const int* __restrict__ xli, int* __restrict__ kcnt) {
  int i = blockIdx.x * blockDim.x + threadIdx.x;
  atomicAdd(&kcnt[xli[i]], 1);
}

__global__ __launch_bounds__(1024) void k_scan_bins(const int* __restrict__ kcnt,
                                                    uint32_t* __restrict__ boffs) {
  __shared__ uint32_t part[1024];
  int tid = threadIdx.x;
  uint32_t c0 = (uint32_t)kcnt[2 * tid];
  uint32_t c1 = (uint32_t)kcnt[2 * tid + 1];
  part[tid] = c0 + c1;
  __syncthreads();
  for (int off = 1; off < 1024; off <<= 1) {
    uint32_t v = (tid >= off) ? part[tid - off] : 0u;
    __syncthreads();
    part[tid] += v;
    __syncthreads();
  }
  uint32_t run = (tid > 0) ? part[tid - 1] : 0u;
  boffs[2 * tid] = run;
  boffs[2 * tid + 1] = run + c0;
}

__global__ void k_scatter_rows(const int* __restrict__ xli, const uint32_t* __restrict__ boffs,
                               uint32_t* __restrict__ bcur, uint32_t* __restrict__ rowlist) {
  int i = blockIdx.x * blockDim.x + threadIdx.x;
  int b = xli[i];
  uint32_t pos = boffs[b] + atomicAdd(&bcur[b], 1u);
  rowlist[pos] = (uint32_t)i;
}

// one bin per block; 4 waves stride the bin's row list; lane = dim column.
// fp64 accumulate -> result independent of scatter order to f32 rounding.
__global__ __launch_bounds__(256) void k_segsum(
    const uint32_t* __restrict__ rowlist, const uint32_t* __restrict__ boffs,
    const int* __restrict__ kcnt, const float* __restrict__ x,
    float* __restrict__ ksum) {
  __shared__ double part[3][64];
  int bin = blockIdx.x;
  int lane = threadIdx.x & 63, w = threadIdx.x >> 6;
  uint32_t start = boffs[bin];
  uint32_t n = (uint32_t)kcnt[bin];
  double s = 0.0;
  for (uint32_t i = w; i < n; i += 4) {
    uint32_t row = rowlist[start + i];
    s += (double)x[(size_t)row * DIM + lane];
  }
  if (w) part[w - 1][lane] = s;
  __syncthreads();
  if (w == 0) {
    s += part[0][lane] + part[1][lane] + part[2][lane];
    ksum[(size_t)bin * DIM + lane] = (float)s;
  }
}

// ---- JAX threefry permutation replication ----

__global__ void k_bits(int which, uint32_t* __restrict__ bits) {
  uint32_t a0, a1, b0, b1;
  threefry2x32(0u, 42u, 0u, 2u, a0, b0);
  threefry2x32(0u, 42u, 1u, 3u, a1, b1);
  uint32_t k0, k1;
  if (which == 0) { k0 = b0; k1 = b1; }
  else {
    uint32_t c0, c1, d0, d1;
    threefry2x32(a0, a1, 0u, 2u, c0, d0);
    threefry2x32(a0, a1, 1u, 3u, c1, d1);
    k0 = d0; k1 = d1;
  }
  int i = blockIdx.x * blockDim.x + threadIdx.x;  // 65536 threads
  uint32_t y0, y1;
  threefry2x32(k0, k1, (uint32_t)i, (uint32_t)(i + 65536), y0, y1);
  bits[i] = y0;
  bits[i + 65536] = y1;
}

__global__ void k_hist(const uint32_t* __restrict__ bits, uint32_t* __restrict__ hist) {
  int i = blockIdx.x * blockDim.x + threadIdx.x;
  atomicAdd(&hist[bits[i] >> 16], 1u);
}

__global__ __launch_bounds__(1024) void k_scan(const uint32_t* __restrict__ hist,
                                               uint32_t* __restrict__ prefix) {
  __shared__ uint32_t part[1024];
  int tid = threadIdx.x;
  int base = tid * 64;
  uint32_t s = 0;
  for (int j = 0; j < 64; ++j) s += hist[base + j];
  part[tid] = s;
  __syncthreads();
  for (int off = 1; off < 1024; off <<= 1) {
    uint32_t v = (tid >= off) ? part[tid - off] : 0u;
    __syncthreads();
    part[tid] += v;
    __syncthreads();
  }
  uint32_t run = (tid > 0) ? part[tid - 1] : 0u;
  for (int j = 0; j < 64; ++j) { prefix[base + j] = run; run += hist[base + j]; }
}

__global__ void k_scatter(const uint32_t* __restrict__ bits, const uint32_t* __restrict__ prefix,
                          uint32_t* __restrict__ cursor, uint32_t* __restrict__ pkey,
                          uint32_t* __restrict__ pidx) {
  int i = blockIdx.x * blockDim.x + threadIdx.x;
  uint32_t key = bits[i];
  uint32_t bin = key >> 16;
  uint32_t pos = prefix[bin] + atomicAdd(&cursor[bin], 1u);
  pkey[pos] = key; pidx[pos] = (uint32_t)i;
}

__global__ void k_rank(const uint32_t* __restrict__ pkey, const uint32_t* __restrict__ pidx,
                       const uint32_t* __restrict__ prefix, const uint32_t* __restrict__ cursor,
                       const uint32_t* __restrict__ srcvals, uint32_t* __restrict__ outv,
                       int limit) {
  int s = blockIdx.x * blockDim.x + threadIdx.x;
  uint32_t myk = pkey[s], myi = pidx[s];
  uint32_t bin = myk >> 16;
  uint32_t start = prefix[bin], cntb = cursor[bin];
  uint32_t r = 0;
  for (uint32_t t = 0; t < cntb; ++t) {
    uint32_t ok = pkey[start + t], oi = pidx[start + t];
    r += (ok < myk || (ok == myk && oi < myi)) ? 1u : 0u;
  }
  uint32_t pos = start + r;
  uint32_t val = srcvals ? srcvals[myi] : myi;
  if (limit == 0) outv[pos] = val;
  else if (pos < (uint32_t)limit) outv[pos] = val;
}

__global__ void k_krand(const uint32_t* __restrict__ perm, const float* __restrict__ x,
                        float* __restrict__ krand) {
  int e = blockIdx.x * blockDim.x + threadIdx.x;
  int b = e >> 6, c = e & 63;
  krand[e] = x[(size_t)perm[b] * DIM + c];
}

__global__ __launch_bounds__(1024) void k_bins(
    const int* __restrict__ kcnt, const float* __restrict__ k_elem_in,
    float* __restrict__ out, double* __restrict__ dbl, int* __restrict__ iacc) {
  __shared__ float ent_l[1024];
  __shared__ int u1_l[1024], u2_l[1024];
  const float OMF = (float)(1.0 - 0.99);
  int tid = threadIdx.x;
  float ent = 0.f; int used = 0, usage = 0;
  #pragma unroll
  for (int t = 0; t < 2; ++t) {
    int b = tid + t * 1024;
    float cnt = (float)kcnt[b];
    float ke = 0.99f * k_elem_in[b] + OMF * cnt;
    out[O_NKE + b] = ke;
    float p = cnt * (1.f / 131072.f);
    ent -= p * logf(p + 1e-8f);
    used += (cnt >= 1.f) ? 1 : 0;
    usage += (ke >= 1.f) ? 1 : 0;
  }
  ent_l[tid] = ent; u1_l[tid] = used; u2_l[tid] = usage;
  __syncthreads();
  for (int off = 512; off > 0; off >>= 1) {
    if (tid < off) {
      ent_l[tid] += ent_l[tid + off];
      u1_l[tid] += u1_l[tid + off];
      u2_l[tid] += u2_l[tid + off];
    }
    __syncthreads();
  }
  if (tid == 0) { dbl[5] = (double)ent_l[0]; iacc[0] = u1_l[0]; iacc[1] = u2_l[0]; }
}

__global__ __launch_bounds__(256) void k_elem_kernel(
    const float* __restrict__ ksum_part, const int* __restrict__ kcnt,
    const float* __restrict__ k_sum_in, const float* __restrict__ k_elem_in,
    const float* __restrict__ k_in, const float* __restrict__ krand,
    float* __restrict__ out, double* __restrict__ dbl) {
  __shared__ float lds[8];
  const float OMF = (float)(1.0 - 0.99);
  int e = blockIdx.x * blockDim.x + threadIdx.x;
  int b = e >> 6;
  float nks = 0.99f * k_sum_in[e] + OMF * ksum_part[e];
  out[O_NKS + e] = nks;
  float cnt = (float)kcnt[b];
  float ke = 0.99f * k_elem_in[b] + OMF * cnt;
  float nk = (ke >= 1.f) ? (nks / ke) : krand[e];
  out[O_NK + e] = nk;
  float dd = nk - k_in[e];
  float bsum = block_reduce_sum(dd * dd, lds);
  if (threadIdx.x == 0) atomicAdd(&dbl[4], (double)bsum);
}

__global__ void k_scal(const double* __restrict__ dbl, const int* __restrict__ iacc,
                       float* __restrict__ out) {
  double M = (double)M_ELEMS;
  double sumS = dbl[0], sumQ = dbl[1];
  double var = (sumQ - sumS * sumS / M) / M;
  out[O_PRE] = (float)sqrt(var > 0.0 ? var : 0.0);
  out[O_FIT] = (float)(dbl[2] / (double)N_ROWS);
  out[O_CL]  = (float)(dbl[2] / M);
  out[O_DK]  = (float)sqrt(dbl[4] / (double)(KB * DIM));
  out[O_ENT] = (float)dbl[5];
  out[O_USED] = (float)iacc[0];
  out[O_UTOT] = (float)iacc[1];
}

// ======================= launch =======================

extern "C" void kernel_launch(void* const* d_in, const int* in_sizes, int n_in,
                              void* d_out, int out_size, void* d_ws, size_t ws_size,
                              hipStream_t stream) {
  (void)in_sizes; (void)n_in; (void)out_size; (void)ws_size;
  const float* x      = (const float*)d_in[0];
  const float* k      = (const float*)d_in[1];
  const float* k_sum  = (const float*)d_in[2];
  const float* k_elem = (const float*)d_in[3];
  float* out = (float*)d_out;
  char* ws = (char*)d_ws;

  double*   dbl   = (double*)(ws + A_DBL);
  int*      iacc  = (int*)(ws + A_IACC);
  int*      cnt   = (int*)(ws + A_CNT);
  float*    kk2n  = (float*)(ws + A_KK2N);
  unsigned short* kh = (unsigned short*)(ws + A_KH);
  unsigned short* kl = (unsigned short*)(ws + A_KL);
  int*      xli   = (int*)(ws + A_XLI);
  float*    ksum  = (float*)(ws + A_KSUM);
  int*      kcnt  = (int*)(ws + A_KCNT);
  float*    krand = (float*)(ws + A_KRAND);
  uint32_t* perm  = (uint32_t*)(ws + A_PERM);
  uint32_t* pj1   = (uint32_t*)(ws + A_PJ1);
  float*    pb1   = (float*)(ws + A_PB1);
  float*    pb2   = (float*)(ws + A_PB2);
  uint32_t* flag  = (uint32_t*)(ws + A_FLAG);
  uint32_t* rowl  = (uint32_t*)(ws + A_ROWL);
  uint32_t* boffs = (uint32_t*)(ws + A_BOFF);
  uint32_t* bcur  = (uint32_t*)(ws + A_BCUR);
  uint32_t* bits  = (uint32_t*)(ws + A_BITS);
  uint32_t* hist  = (uint32_t*)(ws + A_HIST);
  uint32_t* pref  = (uint32_t*)(ws + A_PREF);
  uint32_t* cur   = (uint32_t*)(ws + A_CUR);
  uint32_t* pkey  = (uint32_t*)(ws + A_PKEY);
  uint32_t* pidx  = (uint32_t*)(ws + A_PIDX);
  uint32_t* res1  = (uint32_t*)(ws + A_RES1);

  hipMemsetAsync(ws + A_DBL, 0, 192, stream);  // dbl + iacc + cnt

  k_knorm<<<8, 256, 0, stream>>>(k, kk2n);
  k_decomp<<<512, 256, 0, stream>>>(k, kh, kl);
  k_prenorm<<<1024, 256, 0, stream>>>(x, dbl);
  k_main<<<512, 256, 0, stream>>>(x, kh, kl, kk2n, pb1, pb2, pj1);
  k_flag<<<512, 256, 0, stream>>>(pb1, pb2, pj1, xli, flag, cnt);
  k_rescan<<<256, 256, 0, stream>>>(flag, cnt, x, k, xli);
  k_finish<<<512, 256, 0, stream>>>(x, k, xli, out, dbl);

  // segment sum via counting sort (pb1/pb2 regions are dead now)
  hipMemsetAsync(ws + A_KCNT, 0, 8192, stream);
  hipMemsetAsync(ws + A_BCUR, 0, 8192, stream);
  k_hist_rows<<<512, 256, 0, stream>>>(xli, kcnt);
  k_scan_bins<<<1, 1024, 0, stream>>>(kcnt, boffs);
  k_scatter_rows<<<512, 256, 0, stream>>>(xli, boffs, bcur, rowl);
  k_segsum<<<KB, 256, 0, stream>>>(rowl, boffs, kcnt, x, ksum);

  // jax.random.permutation(key(42), 131072): 2 stable sort rounds
  k_bits<<<256, 256, 0, stream>>>(0, bits);
  hipMemsetAsync(ws + A_HIST, 0, 786432, stream);
  k_hist<<<512, 256, 0, stream>>>(bits, hist);
  k_scan<<<1, 1024, 0, stream>>>(hist, pref);
  k_scatter<<<512, 256, 0, stream>>>(bits, pref, cur, pkey, pidx);
  k_rank<<<512, 256, 0, stream>>>(pkey, pidx, pref, cur, nullptr, res1, 0);
  k_bits<<<256, 256, 0, stream>>>(1, bits);
  hipMemsetAsync(ws + A_HIST, 0, 786432, stream);
  k_hist<<<512, 256, 0, stream>>>(bits, hist);
  k_scan<<<1, 1024, 0, stream>>>(hist, pref);
  k_scatter<<<512, 256, 0, stream>>>(bits, pref, cur, pkey, pidx);
  k_rank<<<512, 256, 0, stream>>>(pkey, pidx, pref, cur, res1, perm, 2048);
  k_krand<<<512, 256, 0, stream>>>(perm, x, krand);

  k_bins<<<1, 1024, 0, stream>>>(kcnt, k_elem, out, dbl, iacc);
  k_elem_kernel<<<512, 256, 0, stream>>>(ksum, kcnt, k_sum, k_elem, k, krand, out, dbl);
  k_scal<<<1, 1, 0, stream>>>(dbl, iacc, out);
}

// Round 5
// 504.692 us; speedup vs baseline: 4.8091x; 1.5691x over previous
//
#include <hip/hip_runtime.h>
#include <stdint.h>

#define N_ROWS 131072
#define DIM 64
#define KB 2048
#define M_ELEMS 8388608  // N_ROWS*DIM

// ---- output offsets (float32 elements, concatenated in return order) ----
#define O_XL   0
#define O_XD   131072
#define O_CL   8519680
#define O_FIT  8519681
#define O_PRE  8519682
#define O_ENT  8519683
#define O_USED 8519684
#define O_UTOT 8519685
#define O_DK   8519686
#define O_NK   8519687
#define O_NKS  8650759
#define O_NKE  8781831

// ---- workspace byte offsets (total must stay <= 5267616, proven in r1) ----
#define A_DBL   0         // doubles: [0]=sumS,[1]=sumQ,[2]=sum cl,[4]=dk acc,[5]=entropy
#define A_IACC  64        // 2 ints
#define A_CNT   128       // rescan counter
#define A_KK2N  192       // 2048 f32 : -0.5*|k|^2
#define A_KH    8384      // 2048*64 bf16
#define A_KL    270528    // 2048*64 bf16
#define A_XLI   532672    // 131072 i32
#define A_KSUM  1056960   // 131072 f32
#define A_KCNT  1581248   // 2048 i32
#define A_KRAND 1589440   // 131072 f32
#define A_PERM  2113728   // 2048 u32
// phase A (argmin) region:
#define A_PJ1   2121920   // 131072 u32
#define A_PB1   2646208   // 131072 f32
#define A_PB2   3170496   // 131072 f32
#define A_FLAG  3694784   // 131072 u32
// phase A2 (segment sum) overlays regions dead after k_flag/k_rescan:
#define A_ROWL  2121920   // 131072 u32 rowlist          (overlays pj1)
#define A_KS64  2646208   // 131072 f64 accumulator (1MB) (overlays pb1+pb2)
#define A_BOFF  4219072   // 2048 u32 bin offsets
#define A_BCUR  4227264   // 2048 u32 bin cursors
// phase B (RNG) overlays phase A (temporally disjoint):
#define A_BITS  2121920   // 131072 u32
#define A_HIST  2646208   // 65536 u32
#define A_PREF  2908352   // 65536 u32
#define A_CUR   3170496   // 65536 u32
#define A_PKEY  3432640   // 131072 u32
#define A_PIDX  3956928   // 131072 u32
#define A_RES1  4481216   // 131072 u32
#define WS_TOTAL 5005504

typedef short bf16x8 __attribute__((ext_vector_type(8)));
typedef float f32x4 __attribute__((ext_vector_type(4)));

// ======================= helpers =======================

__device__ __forceinline__ float block_reduce_sum(float v, float* lds) {
  #pragma unroll
  for (int off = 32; off > 0; off >>= 1) v += __shfl_down(v, off, 64);
  int lane = threadIdx.x & 63, wid = threadIdx.x >> 6;
  if (lane == 0) lds[wid] = v;
  __syncthreads();
  float r = 0.f;
  if (threadIdx.x == 0) {
    int nw = blockDim.x >> 6;
    for (int i = 0; i < nw; ++i) r += lds[i];
  }
  __syncthreads();
  return r;  // valid on thread 0
}

__device__ __forceinline__ unsigned short f2bf_rne(float f) {
  uint32_t u = __float_as_uint(f);
  uint32_t r = u + 0x7FFFu + ((u >> 16) & 1u);
  return (unsigned short)(r >> 16);
}

#define TF_ROUND(r) do { x0 += x1; x1 = (x1 << (r)) | (x1 >> (32 - (r))); x1 ^= x0; } while (0)

__device__ __forceinline__ void threefry2x32(uint32_t k0, uint32_t k1,
                                             uint32_t c0, uint32_t c1,
                                             uint32_t& o0, uint32_t& o1) {
  uint32_t k2 = k0 ^ k1 ^ 0x1BD11BDAu;
  uint32_t x0 = c0 + k0, x1 = c1 + k1;
  TF_ROUND(13); TF_ROUND(15); TF_ROUND(26); TF_ROUND(6);
  x0 += k1; x1 += k2 + 1u;
  TF_ROUND(17); TF_ROUND(29); TF_ROUND(16); TF_ROUND(24);
  x0 += k2; x1 += k0 + 2u;
  TF_ROUND(13); TF_ROUND(15); TF_ROUND(26); TF_ROUND(6);
  x0 += k0; x1 += k1 + 3u;
  TF_ROUND(17); TF_ROUND(29); TF_ROUND(16); TF_ROUND(24);
  x0 += k1; x1 += k2 + 4u;
  TF_ROUND(13); TF_ROUND(15); TF_ROUND(26); TF_ROUND(6);
  x0 += k2; x1 += k0 + 5u;
  o0 = x0; o1 = x1;
}

// ======================= codebook prep =======================

__global__ void k_knorm(const float* __restrict__ k, float* __restrict__ kk2n) {
  int j = blockIdx.x * blockDim.x + threadIdx.x;
  if (j >= KB) return;
  const float4* kp = (const float4*)(k + (size_t)j * DIM);
  float a = 0.f, b = 0.f, c = 0.f, d = 0.f;
  #pragma unroll
  for (int q = 0; q < 16; ++q) {
    float4 v = kp[q];
    a = fmaf(v.x, v.x, a); b = fmaf(v.y, v.y, b);
    c = fmaf(v.z, v.z, c); d = fmaf(v.w, v.w, d);
  }
  kk2n[j] = -0.5f * ((a + b) + (c + d));
}

__global__ void k_decomp(const float* __restrict__ k, unsigned short* __restrict__ kh,
                         unsigned short* __restrict__ kl) {
  int e = blockIdx.x * blockDim.x + threadIdx.x;  // 131072 elements
  float v = k[e];
  unsigned short h = f2bf_rne(v);
  float hf = __uint_as_float((uint32_t)h << 16);
  kh[e] = h;
  kl[e] = f2bf_rne(v - hf);
}

__global__ __launch_bounds__(256) void k_prenorm(const float* __restrict__ x,
                                                 double* __restrict__ dbl) {
  __shared__ float lds[8];
  int gid = blockIdx.x * blockDim.x + threadIdx.x;
  const float4* xp = (const float4*)x;
  int base = gid * 8;
  float s = 0.f, q = 0.f;
  #pragma unroll
  for (int i = 0; i < 8; ++i) {
    float4 v = xp[base + i];
    s += (v.x + v.y) + (v.z + v.w);
    q = fmaf(v.x, v.x, q); q = fmaf(v.y, v.y, q);
    q = fmaf(v.z, v.z, q); q = fmaf(v.w, v.w, q);
  }
  float bs = block_reduce_sum(s, lds);
  float bq = block_reduce_sum(q, lds);
  if (threadIdx.x == 0) {
    atomicAdd(&dbl[0], (double)bs);
    atomicAdd(&dbl[1], (double)bq);
  }
}

// ======================= MFMA argmin =======================
// S^T[code][xrow] = dot(k_code, x_row) - 0.5|k_code|^2, split-bf16:
// S = xh*kh + xh*kl + xl*kh (error ~1e-4 << 0.01 flag window).
__global__ __launch_bounds__(256) void k_main(
    const float* __restrict__ x, const unsigned short* __restrict__ kh,
    const unsigned short* __restrict__ kl, const float* __restrict__ kk2n,
    float* __restrict__ pb1, float* __restrict__ pb2, uint32_t* __restrict__ pj1) {
  int lane = threadIdx.x & 63;
  int wid = threadIdx.x >> 6;
  int lrow = lane & 15;
  int lk = lane >> 4;          // 0..3
  int lbase = lk * 4;
  int r0 = (blockIdx.x * 4 + wid) * 64;

  bf16x8 xh[4][2], xl[4][2];
  #pragma unroll
  for (int g = 0; g < 4; ++g) {
    #pragma unroll
    for (int kt = 0; kt < 2; ++kt) {
      const float* xp = x + (size_t)(r0 + g * 16 + lrow) * DIM + kt * 32 + lk * 8;
      float4 v0 = *(const float4*)xp;
      float4 v1 = *(const float4*)(xp + 4);
      float vv[8] = {v0.x, v0.y, v0.z, v0.w, v1.x, v1.y, v1.z, v1.w};
      #pragma unroll
      for (int i = 0; i < 8; ++i) {
        unsigned short h = f2bf_rne(vv[i]);
        float hf = __uint_as_float((uint32_t)h << 16);
        xh[g][kt][i] = (short)h;
        xl[g][kt][i] = (short)f2bf_rne(vv[i] - hf);
      }
    }
  }

  float b1[4], b2[4];
  uint32_t j1[4];
  #pragma unroll
  for (int g = 0; g < 4; ++g) { b1[g] = -3.402823466e38f; b2[g] = -3.402823466e38f; j1[g] = 0; }

  for (int t = 0; t < KB / 16; ++t) {
    int c0 = t * 16;
    size_t abase = (size_t)(c0 + lrow) * DIM + lk * 8;
    bf16x8 ah0 = *(const bf16x8*)(kh + abase);
    bf16x8 ah1 = *(const bf16x8*)(kh + abase + 32);
    bf16x8 al0 = *(const bf16x8*)(kl + abase);
    bf16x8 al1 = *(const bf16x8*)(kl + abase + 32);
    f32x4 kkv = *(const f32x4*)(kk2n + c0 + lbase);
    uint32_t jb = (uint32_t)(c0 + lbase);
    #pragma unroll
    for (int g = 0; g < 4; ++g) {
      f32x4 acc = __builtin_amdgcn_mfma_f32_16x16x32_bf16(ah0, xh[g][0], kkv, 0, 0, 0);
      acc = __builtin_amdgcn_mfma_f32_16x16x32_bf16(ah1, xh[g][1], acc, 0, 0, 0);
      acc = __builtin_amdgcn_mfma_f32_16x16x32_bf16(al0, xh[g][0], acc, 0, 0, 0);
      acc = __builtin_amdgcn_mfma_f32_16x16x32_bf16(al1, xh[g][1], acc, 0, 0, 0);
      acc = __builtin_amdgcn_mfma_f32_16x16x32_bf16(ah0, xl[g][0], acc, 0, 0, 0);
      acc = __builtin_amdgcn_mfma_f32_16x16x32_bf16(ah1, xl[g][1], acc, 0, 0, 0);
      #pragma unroll
      for (int reg = 0; reg < 4; ++reg) {
        float v = acc[reg];
        bool gt = v > b1[g];
        float mn = fminf(v, b1[g]);
        b2[g] = fmaxf(b2[g], mn);
        b1[g] = gt ? v : b1[g];
        j1[g] = gt ? (jb + (uint32_t)reg) : j1[g];
      }
    }
  }

  #pragma unroll
  for (int g = 0; g < 4; ++g) {
    #pragma unroll
    for (int s = 16; s <= 32; s <<= 1) {
      float ob1 = __shfl_xor(b1[g], s, 64);
      float ob2 = __shfl_xor(b2[g], s, 64);
      uint32_t oj1 = __shfl_xor(j1[g], s, 64);
      bool gt = ob1 > b1[g];
      float mn = fminf(b1[g], ob1);
      b2[g] = fmaxf(fmaxf(b2[g], ob2), mn);
      b1[g] = fmaxf(b1[g], ob1);
      j1[g] = gt ? oj1 : j1[g];
    }
    if (lk == 0) {
      int row = r0 + g * 16 + lrow;
      pb1[row] = b1[g];
      pb2[row] = b2[g];
      pj1[row] = j1[g];
    }
  }
}

__global__ void k_flag(const float* __restrict__ pb1, const float* __restrict__ pb2,
                       const uint32_t* __restrict__ pj1, int* __restrict__ xli,
                       uint32_t* __restrict__ flag, int* __restrict__ cnt) {
  int row = blockIdx.x * blockDim.x + threadIdx.x;
  xli[row] = (int)pj1[row];
  if (pb1[row] - pb2[row] < 0.01f) {  // score gap = dist gap / 2
    int i = atomicAdd(cnt, 1);
    flag[i] = row;
  }
}

// exact fp64 full rescan for near-tie rows; one wave per row
__global__ __launch_bounds__(256) void k_rescan(
    const uint32_t* __restrict__ flag, const int* __restrict__ cnt,
    const float* __restrict__ x, const float* __restrict__ k,
    int* __restrict__ xli) {
  __shared__ float xs[4][64];
  int lane = threadIdx.x & 63;
  int wid = threadIdx.x >> 6;
  int gw = (blockIdx.x * blockDim.x + threadIdx.x) >> 6;
  int n = *cnt;
  for (int fi = gw; fi < n; fi += 1024) {
    int row = flag[fi];
    xs[wid][lane] = x[(size_t)row * DIM + lane];  // wave-synchronous LDS
    double bd = 1e300;
    int bj = 0;
    for (int j = lane; j < KB; j += 64) {
      const float* kr = k + (size_t)j * DIM;
      double e = 0.0;
      #pragma unroll
      for (int d = 0; d < DIM; ++d) {
        double diff = (double)xs[wid][d] - (double)kr[d];
        e = fma(diff, diff, e);
      }
      if (e < bd) { bd = e; bj = j; }
    }
    #pragma unroll
    for (int off = 32; off > 0; off >>= 1) {
      double od = __shfl_down(bd, off, 64);
      int oj = __shfl_down(bj, off, 64);
      if (od < bd || (od == bd && oj < bj)) { bd = od; bj = oj; }
    }
    if (lane == 0) xli[row] = bj;
  }
}

__global__ __launch_bounds__(256) void k_finish(
    const float* __restrict__ x, const float* __restrict__ k,
    const int* __restrict__ xli, float* __restrict__ out,
    double* __restrict__ dbl) {
  __shared__ float lds[8];
  int row = blockIdx.x * blockDim.x + threadIdx.x;
  int j = xli[row];
  out[O_XL + row] = (float)j;
  const float4* xp = (const float4*)(x + (size_t)row * DIM);
  const float4* kp = (const float4*)(k + (size_t)j * DIM);
  float4* xd = (float4*)(out + O_XD + (size_t)row * DIM);
  float a = 0.f, b = 0.f, c = 0.f, d = 0.f;
  #pragma unroll
  for (int q = 0; q < 16; ++q) {
    float4 kv = kp[q];
    float4 xv = xp[q];
    xd[q] = kv;
    float dx = kv.x - xv.x, dy = kv.y - xv.y;
    float dz = kv.z - xv.z, dw = kv.w - xv.w;
    a = fmaf(dx, dx, a); b = fmaf(dy, dy, b);
    c = fmaf(dz, dz, c); d = fmaf(dw, dw, d);
  }
  float cl = (a + b) + (c + d);    // == min dist (fit & commit share this)
  float bc = block_reduce_sum(cl, lds);
  if (threadIdx.x == 0) atomicAdd(&dbl[2], (double)bc);
}

// ======================= segment sum via counting sort =======================

__global__ void k_hist_rows(const int* __restrict__ xli, int* __restrict__ kcnt) {
  int i = blockIdx.x * blockDim.x + threadIdx.x;
  atomicAdd(&kcnt[xli[i]], 1);
}

__global__ __launch_bounds__(1024) void k_scan_bins(const int* __restrict__ kcnt,
                                                    uint32_t* __restrict__ boffs) {
  __shared__ uint32_t part[1024];
  int tid = threadIdx.x;
  uint32_t c0 = (uint32_t)kcnt[2 * tid];
  uint32_t c1 = (uint32_t)kcnt[2 * tid + 1];
  part[tid] = c0 + c1;
  __syncthreads();
  for (int off = 1; off < 1024; off <<= 1) {
    uint32_t v = (tid >= off) ? part[tid - off] : 0u;
    __syncthreads();
    part[tid] += v;
    __syncthreads();
  }
  uint32_t run = (tid > 0) ? part[tid - 1] : 0u;
  boffs[2 * tid] = run;
  boffs[2 * tid + 1] = run + c0;
}

__global__ void k_scatter_rows(const int* __restrict__ xli, const uint32_t* __restrict__ boffs,
                               uint32_t* __restrict__ bcur, uint32_t* __restrict__ rowlist) {
  int i = blockIdx.x * blockDim.x + threadIdx.x;
  int b = xli[i];
  uint32_t pos = boffs[b] + atomicAdd(&bcur[b], 1u);
  rowlist[pos] = (uint32_t)i;
}

// equal-work segment sum: one wave per 16 rowlist positions; lane = dim column.
// fp64 run-accumulate per bin, flush on bin change (rowlist is bin-sorted).
__global__ __launch_bounds__(256) void k_segsum(
    const uint32_t* __restrict__ rowlist, const int* __restrict__ xli,
    const float* __restrict__ x, double* __restrict__ ks64) {
  int gw = (blockIdx.x * blockDim.x + threadIdx.x) >> 6;  // 8192 waves
  int lane = threadIdx.x & 63;
  uint32_t p0 = (uint32_t)gw * 16;
  double acc = 0.0;
  int cur = -1;
  #pragma unroll 4
  for (int i = 0; i < 16; ++i) {
    uint32_t row = rowlist[p0 + i];
    int bin = xli[row];
    if (bin != cur) {
      if (cur >= 0) atomicAdd(&ks64[(size_t)cur * DIM + lane], acc);
      acc = 0.0; cur = bin;
    }
    acc += (double)x[(size_t)row * DIM + lane];
  }
  if (cur >= 0) atomicAdd(&ks64[(size_t)cur * DIM + lane], acc);
}

__global__ void k_seg_conv(const double* __restrict__ ks64, float* __restrict__ ksum) {
  int e = blockIdx.x * blockDim.x + threadIdx.x;
  ksum[e] = (float)ks64[e];
}

// ---- JAX threefry permutation replication ----

__global__ void k_bits(int which, uint32_t* __restrict__ bits) {
  uint32_t a0, a1, b0, b1;
  threefry2x32(0u, 42u, 0u, 2u, a0, b0);
  threefry2x32(0u, 42u, 1u, 3u, a1, b1);
  uint32_t k0, k1;
  if (which == 0) { k0 = b0; k1 = b1; }
  else {
    uint32_t c0, c1, d0, d1;
    threefry2x32(a0, a1, 0u, 2u, c0, d0);
    threefry2x32(a0, a1, 1u, 3u, c1, d1);
    k0 = d0; k1 = d1;
  }
  int i = blockIdx.x * blockDim.x + threadIdx.x;  // 65536 threads
  uint32_t y0, y1;
  threefry2x32(k0, k1, (uint32_t)i, (uint32_t)(i + 65536), y0, y1);
  bits[i] = y0;
  bits[i + 65536] = y1;
}

__global__ void k_hist(const uint32_t* __restrict__ bits, uint32_t* __restrict__ hist) {
  int i = blockIdx.x * blockDim.x + threadIdx.x;
  atomicAdd(&hist[bits[i] >> 16], 1u);
}

__global__ __launch_bounds__(1024) void k_scan(const uint32_t* __restrict__ hist,
                                               uint32_t* __restrict__ prefix) {
  __shared__ uint32_t part[1024];
  int tid = threadIdx.x;
  int base = tid * 64;
  uint32_t s = 0;
  for (int j = 0; j < 64; ++j) s += hist[base + j];
  part[tid] = s;
  __syncthreads();
  for (int off = 1; off < 1024; off <<= 1) {
    uint32_t v = (tid >= off) ? part[tid - off] : 0u;
    __syncthreads();
    part[tid] += v;
    __syncthreads();
  }
  uint32_t run = (tid > 0) ? part[tid - 1] : 0u;
  for (int j = 0; j < 64; ++j) { prefix[base + j] = run; run += hist[base + j]; }
}

__global__ void k_scatter(const uint32_t* __restrict__ bits, const uint32_t* __restrict__ prefix,
                          uint32_t* __restrict__ cursor, uint32_t* __restrict__ pkey,
                          uint32_t* __restrict__ pidx) {
  int i = blockIdx.x * blockDim.x + threadIdx.x;
  uint32_t key = bits[i];
  uint32_t bin = key >> 16;
  uint32_t pos = prefix[bin] + atomicAdd(&cursor[bin], 1u);
  pkey[pos] = key; pidx[pos] = (uint32_t)i;
}

__global__ void k_rank(const uint32_t* __restrict__ pkey, const uint32_t* __restrict__ pidx,
                       const uint32_t* __restrict__ prefix, const uint32_t* __restrict__ cursor,
                       const uint32_t* __restrict__ srcvals, uint32_t* __restrict__ outv,
                       int limit) {
  int s = blockIdx.x * blockDim.x + threadIdx.x;
  uint32_t myk = pkey[s], myi = pidx[s];
  uint32_t bin = myk >> 16;
  uint32_t start = prefix[bin], cntb = cursor[bin];
  uint32_t r = 0;
  for (uint32_t t = 0; t < cntb; ++t) {
    uint32_t ok = pkey[start + t], oi = pidx[start + t];
    r += (ok < myk || (ok == myk && oi < myi)) ? 1u : 0u;
  }
  uint32_t pos = start + r;
  uint32_t val = srcvals ? srcvals[myi] : myi;
  if (limit == 0) outv[pos] = val;
  else if (pos < (uint32_t)limit) outv[pos] = val;
}

__global__ void k_krand(const uint32_t* __restrict__ perm, const float* __restrict__ x,
                        float* __restrict__ krand) {
  int e = blockIdx.x * blockDim.x + threadIdx.x;
  int b = e >> 6, c = e & 63;
  krand[e] = x[(size_t)perm[b] * DIM + c];
}

__global__ __launch_bounds__(1024) void k_bins(
    const int* __restrict__ kcnt, const float* __restrict__ k_elem_in,
    float* __restrict__ out, double* __restrict__ dbl, int* __restrict__ iacc) {
  __shared__ float ent_l[1024];
  __shared__ int u1_l[1024], u2_l[1024];
  const float OMF = (float)(1.0 - 0.99);
  int tid = threadIdx.x;
  float ent = 0.f; int used = 0, usage = 0;
  #pragma unroll
  for (int t = 0; t < 2; ++t) {
    int b = tid + t * 1024;
    float cnt = (float)kcnt[b];
    float ke = 0.99f * k_elem_in[b] + OMF * cnt;
    out[O_NKE + b] = ke;
    float p = cnt * (1.f / 131072.f);
    ent -= p * logf(p + 1e-8f);
    used += (cnt >= 1.f) ? 1 : 0;
    usage += (ke >= 1.f) ? 1 : 0;
  }
  ent_l[tid] = ent; u1_l[tid] = used; u2_l[tid] = usage;
  __syncthreads();
  for (int off = 512; off > 0; off >>= 1) {
    if (tid < off) {
      ent_l[tid] += ent_l[tid + off];
      u1_l[tid] += u1_l[tid + off];
      u2_l[tid] += u2_l[tid + off];
    }
    __syncthreads();
  }
  if (tid == 0) { dbl[5] = (double)ent_l[0]; iacc[0] = u1_l[0]; iacc[1] = u2_l[0]; }
}

__global__ __launch_bounds__(256) void k_elem_kernel(
    const float* __restrict__ ksum_part, const int* __restrict__ kcnt,
    const float* __restrict__ k_sum_in, const float* __restrict__ k_elem_in,
    const float* __restrict__ k_in, const float* __restrict__ krand,
    float* __restrict__ out, double* __restrict__ dbl) {
  __shared__ float lds[8];
  const float OMF = (float)(1.0 - 0.99);
  int e = blockIdx.x * blockDim.x + threadIdx.x;
  int b = e >> 6;
  float nks = 0.99f * k_sum_in[e] + OMF * ksum_part[e];
  out[O_NKS + e] = nks;
  float cnt = (float)kcnt[b];
  float ke = 0.99f * k_elem_in[b] + OMF * cnt;
  float nk = (ke >= 1.f) ? (nks / ke) : krand[e];
  out[O_NK + e] = nk;
  float dd = nk - k_in[e];
  float bsum = block_reduce_sum(dd * dd, lds);
  if (threadIdx.x == 0) atomicAdd(&dbl[4], (double)bsum);
}

__global__ void k_scal(const double* __restrict__ dbl, const int* __restrict__ iacc,
                       float* __restrict__ out) {
  double M = (double)M_ELEMS;
  double sumS = dbl[0], sumQ = dbl[1];
  double var = (sumQ - sumS * sumS / M) / M;
  out[O_PRE] = (float)sqrt(var > 0.0 ? var : 0.0);
  out[O_FIT] = (float)(dbl[2] / (double)N_ROWS);
  out[O_CL]  = (float)(dbl[2] / M);
  out[O_DK]  = (float)sqrt(dbl[4] / (double)(KB * DIM));
  out[O_ENT] = (float)dbl[5];
  out[O_USED] = (float)iacc[0];
  out[O_UTOT] = (float)iacc[1];
}

// ======================= launch =======================

extern "C" void kernel_launch(void* const* d_in, const int* in_sizes, int n_in,
                              void* d_out, int out_size, void* d_ws, size_t ws_size,
                              hipStream_t stream) {
  (void)in_sizes; (void)n_in; (void)out_size; (void)ws_size;
  const float* x      = (const float*)d_in[0];
  const float* k      = (const float*)d_in[1];
  const float* k_sum  = (const float*)d_in[2];
  const float* k_elem = (const float*)d_in[3];
  float* out = (float*)d_out;
  char* ws = (char*)d_ws;

  double*   dbl   = (double*)(ws + A_DBL);
  int*      iacc  = (int*)(ws + A_IACC);
  int*      cnt   = (int*)(ws + A_CNT);
  float*    kk2n  = (float*)(ws + A_KK2N);
  unsigned short* kh = (unsigned short*)(ws + A_KH);
  unsigned short* kl = (unsigned short*)(ws + A_KL);
  int*      xli   = (int*)(ws + A_XLI);
  float*    ksum  = (float*)(ws + A_KSUM);
  int*      kcnt  = (int*)(ws + A_KCNT);
  float*    krand = (float*)(ws + A_KRAND);
  uint32_t* perm  = (uint32_t*)(ws + A_PERM);
  uint32_t* pj1   = (uint32_t*)(ws + A_PJ1);
  float*    pb1   = (float*)(ws + A_PB1);
  float*    pb2   = (float*)(ws + A_PB2);
  uint32_t* flag  = (uint32_t*)(ws + A_FLAG);
  uint32_t* rowl  = (uint32_t*)(ws + A_ROWL);
  double*   ks64  = (double*)(ws + A_KS64);
  uint32_t* boffs = (uint32_t*)(ws + A_BOFF);
  uint32_t* bcur  = (uint32_t*)(ws + A_BCUR);
  uint32_t* bits  = (uint32_t*)(ws + A_BITS);
  uint32_t* hist  = (uint32_t*)(ws + A_HIST);
  uint32_t* pref  = (uint32_t*)(ws + A_PREF);
  uint32_t* cur   = (uint32_t*)(ws + A_CUR);
  uint32_t* pkey  = (uint32_t*)(ws + A_PKEY);
  uint32_t* pidx  = (uint32_t*)(ws + A_PIDX);
  uint32_t* res1  = (uint32_t*)(ws + A_RES1);

  hipMemsetAsync(ws + A_DBL, 0, 192, stream);  // dbl + iacc + cnt

  k_knorm<<<8, 256, 0, stream>>>(k, kk2n);
  k_decomp<<<512, 256, 0, stream>>>(k, kh, kl);
  k_prenorm<<<1024, 256, 0, stream>>>(x, dbl);
  k_main<<<512, 256, 0, stream>>>(x, kh, kl, kk2n, pb1, pb2, pj1);
  k_flag<<<512, 256, 0, stream>>>(pb1, pb2, pj1, xli, flag, cnt);
  k_rescan<<<256, 256, 0, stream>>>(flag, cnt, x, k, xli);
  k_finish<<<512, 256, 0, stream>>>(x, k, xli, out, dbl);

  // segment sum via counting sort + equal-work chunked accumulation
  hipMemsetAsync(ws + A_KCNT, 0, 8192, stream);
  hipMemsetAsync(ws + A_BCUR, 0, 8192, stream);
  hipMemsetAsync(ws + A_KS64, 0, 1048576, stream);
  k_hist_rows<<<512, 256, 0, stream>>>(xli, kcnt);
  k_scan_bins<<<1, 1024, 0, stream>>>(kcnt, boffs);
  k_scatter_rows<<<512, 256, 0, stream>>>(xli, boffs, bcur, rowl);
  k_segsum<<<2048, 256, 0, stream>>>(rowl, xli, x, ks64);
  k_seg_conv<<<512, 256, 0, stream>>>(ks64, ksum);

  // jax.random.permutation(key(42), 131072): 2 stable sort rounds
  k_bits<<<256, 256, 0, stream>>>(0, bits);
  hipMemsetAsync(ws + A_HIST, 0, 786432, stream);
  k_hist<<<512, 256, 0, stream>>>(bits, hist);
  k_scan<<<1, 1024, 0, stream>>>(hist, pref);
  k_scatter<<<512, 256, 0, stream>>>(bits, pref, cur, pkey, pidx);
  k_rank<<<512, 256, 0, stream>>>(pkey, pidx, pref, cur, nullptr, res1, 0);
  k_bits<<<256, 256, 0, stream>>>(1, bits);
  hipMemsetAsync(ws + A_HIST, 0, 786432, stream);
  k_hist<<<512, 256, 0, stream>>>(bits, hist);
  k_scan<<<1, 1024, 0, stream>>>(hist, pref);
  k_scatter<<<512, 256, 0, stream>>>(bits, pref, cur, pkey, pidx);
  k_rank<<<512, 256, 0, stream>>>(pkey, pidx, pref, cur, res1, perm, 2048);
  k_krand<<<512, 256, 0, stream>>>(perm, x, krand);

  k_bins<<<1, 1024, 0, stream>>>(kcnt, k_elem, out, dbl, iacc);
  k_elem_kernel<<<512, 256, 0, stream>>>(ksum, kcnt, k_sum, k_elem, k, krand, out, dbl);
  k_scal<<<1, 1, 0, stream>>>(dbl, iacc, out);
}